// Round 12
// baseline (1156.006 us; speedup 1.0000x reference)
//
#include <hip/hip_runtime.h>

#define B_ 128
#define K_ 25
#define DEG_ 16

#define R4(X) X(0) X(1) X(2) X(3)

typedef __attribute__((ext_vector_type(4))) float f32x4;
typedef __attribute__((ext_vector_type(8))) short bf16x8;

__device__ __forceinline__ float4 f4ma(float t, float4 w, float4 a) {
    a.x = fmaf(t, w.x, a.x); a.y = fmaf(t, w.y, a.y);
    a.z = fmaf(t, w.z, a.z); a.w = fmaf(t, w.w, a.w);
    return a;
}
__device__ __forceinline__ float4 f4max(float4 a, float4 b) {
    return make_float4(fmaxf(a.x, b.x), fmaxf(a.y, b.y), fmaxf(a.z, b.z), fmaxf(a.w, b.w));
}
__device__ __forceinline__ float4 f4sub2(float4 s, float4 p) {
    return make_float4(2.f * s.x - p.x, 2.f * s.y - p.y, 2.f * s.z - p.z, 2.f * s.w - p.w);
}
// bf16 pack (RTNE)
__device__ __forceinline__ unsigned f2bfu(float f) {
    unsigned u = __float_as_uint(f);
    return (u + 0x7FFFu + ((u >> 16) & 1u)) >> 16;
}
__device__ __forceinline__ unsigned packbf(float e, float o) { return f2bfu(e) | (f2bfu(o) << 16); }

__device__ __forceinline__ bf16x8 u2b(uint4 u) {
    union { uint4 u4; bf16x8 b8; } c; c.u4 = u; return c.b8;
}
__device__ __forceinline__ f32x4 mfma_bf(uint4 a, uint4 b, f32x4 c) {
    return __builtin_amdgcn_mfma_f32_16x16x32_bf16(u2b(a), u2b(b), c, 0, 0, 0);
}

// ======== layouts (4-col slabs: 2 fi x 2 b) ========
// layer-2: slab s = (fi>>1)*64 + (b>>1), s in [0,1024); elem e = (fi&1)*2 + (b&1)
//   state addr = s*4096 + v*4 + e           (S2 = 1024*4096 floats)
//   mirror dword = s*2048 + v*2 + (b&1), value packbf(fi even, fi odd); slot = S2/2
// layer-3: slab s = (fi>>1)*64 + (b>>1), s in [0,2048)
//   state addr = s*1024 + v*4 + e           (S3 = 2048*1024 floats)
//   mirror dword = s*512 + v*2 + (b&1); slot = S3/2

// ---------------- transpose x: (B=128, N=4096) -> x0 (4096, 128)
__global__ __launch_bounds__(256) void k_transpose_x(const float* __restrict__ x, float* __restrict__ x0) {
    int i = blockIdx.x * 256 + threadIdx.x;   // i = v*128 + b
    int v = i >> 7, b = i & 127;
    x0[i] = x[(b << 12) + v];
}

// ---------------- prepack W2/W3 -> bf16 [k][fo][fi]
__global__ __launch_bounds__(256) void k_packw(const float* __restrict__ w2, const float* __restrict__ w3,
        unsigned short* __restrict__ wb2, unsigned short* __restrict__ wb3) {
    int i = blockIdx.x * 256 + threadIdx.x;
    if (i < 51200) {        // 25*64*32
        int k = i >> 11, rem = i & 2047, fo = rem >> 5, fi = rem & 31;
        wb2[i] = (unsigned short)f2bfu(w2[(size_t)(fi * K_ + k) * 64 + fo]);
    }
    if (i < 102400) {       // 25*64*64
        int k = i >> 12, rem = i & 4095, fo = rem >> 6, fi = rem & 63;
        wb3[i] = (unsigned short)f2bfu(w3[(size_t)(fi * K_ + k) * 64 + fo]);
    }
}

// ---------------- layer-1 SpMM: one wave per row v, lane = float2 column
__global__ __launch_bounds__(256) void k_spmm1(const int* __restrict__ cols, const float* __restrict__ vals,
        const float2* __restrict__ cur, const float2* __restrict__ prev,
        float2* __restrict__ next, int two) {
    int t = blockIdx.x * 256 + threadIdx.x;
    int v = __builtin_amdgcn_readfirstlane(t >> 6);
    int lane = threadIdx.x & 63;
    int base = v * DEG_;
    float2 s = make_float2(0.f, 0.f);
#pragma unroll
    for (int d = 0; d < DEG_; ++d) {
        float wv = vals[base + d];
        float2 xx = cur[((size_t)cols[base + d] << 6) + lane];
        s.x = fmaf(wv, xx.x, s.x); s.y = fmaf(wv, xx.y, s.y);
    }
    size_t idx = ((size_t)v << 6) + lane;
    if (two) {
        float2 p = prev[idx];
        s.x = 2.f * s.x - p.x; s.y = 2.f * s.y - p.y;
    }
    next[idx] = s;
}

// ---------------- layer-2 LDS chain: wg = 4-col slab, single buffer (stride-5 pad), prev in regs
__global__ __launch_bounds__(256) void k_chain2(const int* __restrict__ cols, const float* __restrict__ vals,
        float* __restrict__ stA, float* __restrict__ stB, unsigned* __restrict__ mir,
        int k0, int nsteps) {
    __shared__ float st[5120];
    int s = blockIdx.x, t = threadIdx.x;
    size_t sb = (size_t)s * 4096;
    float4 p0, p1, p2, p3;
#define C2_LD(r, P) { int v = t + (r << 8); \
    *(float4*)&st[v * 5] = *(const float4*)(stA + sb + v * 4); \
    P = *(const float4*)(stB + sb + v * 4); }
    C2_LD(0, p0) C2_LD(1, p1) C2_LD(2, p2) C2_LD(3, p3)
#undef C2_LD
    __syncthreads();
    float4 n0, n1, n2, n3;
    for (int step = 0; step < nsteps; ++step) {
        int k = k0 + step;
        float4 c0, c1, c2, c3;
#define C2_CMP(r, N, C, P) { int v = t + (r << 8); \
    const int4* cp = (const int4*)(cols + v * 16); \
    const float4* vp = (const float4*)(vals + v * 16); \
    float4 a = make_float4(0.f, 0.f, 0.f, 0.f); \
    for (int dd = 0; dd < 4; ++dd) { \
        int4 cc = cp[dd]; float4 ww = vp[dd]; \
        a = f4ma(ww.x, *(const float4*)&st[cc.x * 5], a); \
        a = f4ma(ww.y, *(const float4*)&st[cc.y * 5], a); \
        a = f4ma(ww.z, *(const float4*)&st[cc.z * 5], a); \
        a = f4ma(ww.w, *(const float4*)&st[cc.w * 5], a); \
    } \
    C = *(const float4*)&st[v * 5]; \
    N = (k >= 2) ? f4sub2(a, P) : a; }
        C2_CMP(0, n0, c0, p0) C2_CMP(1, n1, c1, p1) C2_CMP(2, n2, c2, p2) C2_CMP(3, n3, c3, p3)
#undef C2_CMP
        __syncthreads();
        unsigned* ms = mir + (size_t)(k % 5) * 2097152 + (size_t)s * 2048;
#define C2_ST(r, N, C, P) { int v = t + (r << 8); \
    *(float4*)&st[v * 5] = N; \
    *(uint2*)(ms + v * 2) = make_uint2(packbf(N.x, N.z), packbf(N.y, N.w)); \
    P = C; }
        C2_ST(0, n0, c0, p0) C2_ST(1, n1, c1, p1) C2_ST(2, n2, c2, p2) C2_ST(3, n3, c3, p3)
#undef C2_ST
        __syncthreads();
    }
#define C2_OUT(r, N, P) { int v = t + (r << 8); \
    *(float4*)(stA + sb + v * 4) = N; \
    *(float4*)(stB + sb + v * 4) = P; }
    C2_OUT(0, n0, p0) C2_OUT(1, n1, p1) C2_OUT(2, n2, p2) C2_OUT(3, n3, p3)
#undef C2_OUT
}

// ---------------- layer-3 LDS chain: wg = 4-col slab, 256 threads = 256 rows
__global__ __launch_bounds__(256) void k_chain3(const int* __restrict__ cols, const float* __restrict__ vals,
        float* __restrict__ stA, float* __restrict__ stB, unsigned* __restrict__ mir,
        int k0, int nsteps) {
    __shared__ float st[1280];
    int s = blockIdx.x, t = threadIdx.x;   // t = v
    size_t sb = (size_t)s * 1024;
    *(float4*)&st[t * 5] = *(const float4*)(stA + sb + t * 4);
    float4 pr = *(const float4*)(stB + sb + t * 4);
    __syncthreads();
    const int4* cp = (const int4*)(cols + t * 16);
    const float4* vp = (const float4*)(vals + t * 16);
    float4 n;
    for (int step = 0; step < nsteps; ++step) {
        int k = k0 + step;
        float4 a = make_float4(0.f, 0.f, 0.f, 0.f);
        for (int dd = 0; dd < 4; ++dd) {
            int4 cc = cp[dd]; float4 ww = vp[dd];
            a = f4ma(ww.x, *(const float4*)&st[cc.x * 5], a);
            a = f4ma(ww.y, *(const float4*)&st[cc.y * 5], a);
            a = f4ma(ww.z, *(const float4*)&st[cc.z * 5], a);
            a = f4ma(ww.w, *(const float4*)&st[cc.w * 5], a);
        }
        float4 c = *(const float4*)&st[t * 5];
        n = (k >= 2) ? f4sub2(a, pr) : a;
        __syncthreads();
        *(float4*)&st[t * 5] = n;
        unsigned* ms = mir + (size_t)(k % 5) * 1048576 + (size_t)s * 512;
        *(uint2*)(ms + t * 2) = make_uint2(packbf(n.x, n.z), packbf(n.y, n.w));
        pr = c;
        __syncthreads();
    }
    *(float4*)(stA + sb + t * 4) = n;
    *(float4*)(stB + sb + t * 4) = pr;
}

// ---------------- layer 1 projection + bias + relu + pool4 -> layer-2 state + mirror slot0
__global__ __launch_bounds__(256) void k_proj1_pool(const float* __restrict__ basis,
        const float* __restrict__ W1, const float* __restrict__ b1, float* __restrict__ st2,
        unsigned* __restrict__ mir) {
    int half = blockIdx.y;
    int i = blockIdx.x * 256 + threadIdx.x;   // i = g*128 + b; g = layer-2 v
    int g = i >> 7, b = i & 127;
    const float* wbase = W1 + half * 16;
#define P1_DM(j) float4 M##j = make_float4(-1e30f, -1e30f, -1e30f, -1e30f);
    R4(P1_DM)
#undef P1_DM
    for (int r = 0; r < 4; ++r) {
        const float* bp = basis + (((size_t)(4 * g + r) << 7) + b);
#define P1_DC(j) float4 C##j = make_float4(0.f, 0.f, 0.f, 0.f);
        R4(P1_DC)
#undef P1_DC
#pragma unroll 5
        for (int k = 0; k < K_; ++k) {
            float tv = bp[(size_t)k * 524288];
            const float4* w = (const float4*)(wbase + k * 32);
#define P1_FM(j) C##j = f4ma(tv, w[j], C##j);
            R4(P1_FM)
#undef P1_FM
        }
#define P1_MX(j) M##j = f4max(M##j, C##j);
        R4(P1_MX)
#undef P1_MX
    }
    const float* bb = b1 + half * 16;
    int bh = b >> 1, bo = b & 1;
#define P1_ST(j) { \
    float e0 = fmaxf(M##j.x + bb[4*j+0], 0.f); \
    float o0 = fmaxf(M##j.y + bb[4*j+1], 0.f); \
    float e1 = fmaxf(M##j.z + bb[4*j+2], 0.f); \
    float o1 = fmaxf(M##j.w + bb[4*j+3], 0.f); \
    int s2a = (half * 8 + 2 * j) * 64 + bh; \
    float* pa = st2 + (size_t)s2a * 4096 + g * 4 + bo; \
    pa[0] = e0; pa[2] = o0; \
    float* pb = st2 + (size_t)(s2a + 64) * 4096 + g * 4 + bo; \
    pb[0] = e1; pb[2] = o1; \
    mir[(size_t)s2a * 2048 + g * 2 + bo] = packbf(e0, o0); \
    mir[(size_t)(s2a + 64) * 2048 + g * 2 + bo] = packbf(e1, o1); }
    R4(P1_ST)
#undef P1_ST
}

// ---------------- layer-2 chunk projection via MFMA (4-col-slab mirror)
__global__ __launch_bounds__(256) void k_proj_l2m(const unsigned* __restrict__ mir, size_t slotH,
        const uint4* __restrict__ wb, float* __restrict__ acc, int k0, int init,
        const float* __restrict__ bias) {
    int wid = blockIdx.x * 4 + (threadIdx.x >> 6);   // 8192 waves
    int lane = threadIdx.x & 63;
    int lm = lane & 15, lg = lane >> 4;
    int v = wid >> 3, b0 = (wid & 7) << 4;
    float* ap = acc + ((size_t)v << 13) + b0 + (lg << 2);
    f32x4 C0, C1, C2, C3;
    if (init) {
        float q0 = bias[lm], q1 = bias[16 + lm], q2 = bias[32 + lm], q3 = bias[48 + lm];
        C0 = f32x4{q0, q0, q0, q0}; C1 = f32x4{q1, q1, q1, q1};
        C2 = f32x4{q2, q2, q2, q2}; C3 = f32x4{q3, q3, q3, q3};
    } else {
        C0 = *(const f32x4*)(ap + (size_t)lm * 128);
        C1 = *(const f32x4*)(ap + (size_t)(16 + lm) * 128);
        C2 = *(const f32x4*)(ap + (size_t)(32 + lm) * 128);
        C3 = *(const f32x4*)(ap + (size_t)(48 + lm) * 128);
    }
    int b = b0 + lm;
    const unsigned* mp0 = mir + ((size_t)((lg << 2) * 64 + (b >> 1))) * 2048 + (v << 1) + (b & 1);
#pragma unroll
    for (int kk = 0; kk < 5; ++kk) {
        const unsigned* mp = mp0 + (size_t)kk * slotH;
        uint4 a = make_uint4(mp[0], mp[131072], mp[262144], mp[393216]);
        int kb = (k0 + kk) << 6;
        uint4 w0 = wb[(kb + lm) * 4 + lg];
        uint4 w1 = wb[(kb + 16 + lm) * 4 + lg];
        uint4 w2 = wb[(kb + 32 + lm) * 4 + lg];
        uint4 w3 = wb[(kb + 48 + lm) * 4 + lg];
        C0 = mfma_bf(a, w0, C0);
        C1 = mfma_bf(a, w1, C1);
        C2 = mfma_bf(a, w2, C2);
        C3 = mfma_bf(a, w3, C3);
    }
    *(f32x4*)(ap + (size_t)lm * 128) = C0;
    *(f32x4*)(ap + (size_t)(16 + lm) * 128) = C1;
    *(f32x4*)(ap + (size_t)(32 + lm) * 128) = C2;
    *(f32x4*)(ap + (size_t)(48 + lm) * 128) = C3;
}

// ---------------- layer-3 chunk projection via MFMA (4-col-slab mirror)
__global__ __launch_bounds__(256) void k_proj_l3m(const unsigned* __restrict__ mir, size_t slotH,
        const uint4* __restrict__ wb, float* __restrict__ acc, int k0, int init,
        const float* __restrict__ bias, int finalrelu) {
    int wid = blockIdx.x * 4 + (threadIdx.x >> 6);   // 2048 waves
    int lane = threadIdx.x & 63;
    int lm = lane & 15, lg = lane >> 4;
    int v = wid >> 3, b0 = (wid & 7) << 4;
    float* ap = acc + ((size_t)v << 13) + b0 + (lg << 2);
    f32x4 C0, C1, C2, C3;
    if (init) {
        float q0 = bias[lm], q1 = bias[16 + lm], q2 = bias[32 + lm], q3 = bias[48 + lm];
        C0 = f32x4{q0, q0, q0, q0}; C1 = f32x4{q1, q1, q1, q1};
        C2 = f32x4{q2, q2, q2, q2}; C3 = f32x4{q3, q3, q3, q3};
    } else {
        C0 = *(const f32x4*)(ap + (size_t)lm * 128);
        C1 = *(const f32x4*)(ap + (size_t)(16 + lm) * 128);
        C2 = *(const f32x4*)(ap + (size_t)(32 + lm) * 128);
        C3 = *(const f32x4*)(ap + (size_t)(48 + lm) * 128);
    }
    int b = b0 + lm;
    const unsigned* mp0 = mir + (size_t)(b >> 1) * 512 + (v << 1) + (b & 1);
#pragma unroll
    for (int kk = 0; kk < 5; ++kk) {
        const unsigned* mpk = mp0 + (size_t)kk * slotH;
        int kb = (k0 + kk) << 6;
#pragma unroll
        for (int ks = 0; ks < 2; ++ks) {
            const unsigned* mk = mpk + (size_t)((ks << 4) + (lg << 2)) * 32768;
            uint4 a = make_uint4(mk[0], mk[32768], mk[65536], mk[98304]);
            int wof = (ks << 2) + lg;
            uint4 w0 = wb[(kb + lm) * 8 + wof];
            uint4 w1 = wb[(kb + 16 + lm) * 8 + wof];
            uint4 w2 = wb[(kb + 32 + lm) * 8 + wof];
            uint4 w3 = wb[(kb + 48 + lm) * 8 + wof];
            C0 = mfma_bf(a, w0, C0);
            C1 = mfma_bf(a, w1, C1);
            C2 = mfma_bf(a, w2, C2);
            C3 = mfma_bf(a, w3, C3);
        }
    }
    if (finalrelu) {
#pragma unroll
        for (int r = 0; r < 4; ++r) {
            C0[r] = fmaxf(C0[r], 0.f); C1[r] = fmaxf(C1[r], 0.f);
            C2[r] = fmaxf(C2[r], 0.f); C3[r] = fmaxf(C3[r], 0.f);
        }
    }
    *(f32x4*)(ap + (size_t)lm * 128) = C0;
    *(f32x4*)(ap + (size_t)(16 + lm) * 128) = C1;
    *(f32x4*)(ap + (size_t)(32 + lm) * 128) = C2;
    *(f32x4*)(ap + (size_t)(48 + lm) * 128) = C3;
}

// ---------------- relu + pool4: layer-2 acc -> layer-3 state + mirror slot0
__global__ __launch_bounds__(256) void k_relu_pool_m(const float* __restrict__ acc,
        float* __restrict__ st3, unsigned* __restrict__ mir) {
    int i = blockIdx.x * 256 + threadIdx.x;   // g*4096 + fi2*128 + b; g = layer-3 v
    int g = i >> 12, fi2 = (i >> 7) & 31, b = i & 127;
    const float* ap = acc + (((size_t)g << 2) << 13) + (fi2 << 8) + b;
    float me = 0.f, mo = 0.f;
#pragma unroll
    for (int r = 0; r < 4; ++r) {
        me = fmaxf(me, ap[0]); mo = fmaxf(mo, ap[128]);
        ap += 8192;
    }
    int s3 = fi2 * 64 + (b >> 1), bo = b & 1;
    st3[(size_t)s3 * 1024 + g * 4 + bo] = me;
    st3[(size_t)s3 * 1024 + g * 4 + 2 + bo] = mo;
    mir[(size_t)s3 * 512 + g * 2 + bo] = packbf(me, mo);
}

// ---------------- FC1 partials: rowsplit 64, 8 b's per thread
__global__ __launch_bounds__(256) void k_fc1_part(const float* __restrict__ t3, const float* __restrict__ w,
                           float* __restrict__ part) {
    int blk = blockIdx.x;
    int bg = blk >> 7;
    int rs = (blk >> 1) & 63;
    int j = ((blk & 1) << 8) + threadIdx.x;
    int b0 = bg << 3;
    float a0=0.f,a1=0.f,a2=0.f,a3=0.f,a4=0.f,a5=0.f,a6=0.f,a7=0.f;
    int r0 = rs << 8;
#pragma unroll 4
    for (int row = r0; row < r0 + 256; ++row) {
        float wv = w[((size_t)row << 9) + j];
        const float4* tp = (const float4*)(t3 + ((size_t)row << 7) + b0);
        float4 t0 = tp[0], t1 = tp[1];
        a0 = fmaf(t0.x, wv, a0);
        a1 = fmaf(t0.y, wv, a1);
        a2 = fmaf(t0.z, wv, a2);
        a3 = fmaf(t0.w, wv, a3);
        a4 = fmaf(t1.x, wv, a4);
        a5 = fmaf(t1.y, wv, a5);
        a6 = fmaf(t1.z, wv, a6);
        a7 = fmaf(t1.w, wv, a7);
    }
    float* pp = part + (((size_t)(rs << 7) + b0) << 9) + j;
    pp[0*512]=a0; pp[1*512]=a1; pp[2*512]=a2; pp[3*512]=a3;
    pp[4*512]=a4; pp[5*512]=a5; pp[6*512]=a6; pp[7*512]=a7;
}

__global__ __launch_bounds__(256) void k_fc1_red(const float* __restrict__ part, const float* __restrict__ bias,
                          float* __restrict__ h) {
    int i = blockIdx.x * 256 + threadIdx.x;   // i = b*512 + j
    float a = bias[i & 511];
#pragma unroll 8
    for (int rs = 0; rs < 64; ++rs) a += part[((size_t)rs << 16) + i];
    h[i] = a;
}

// ---------------- batchnorm stats over batch (biased var), store mean | inv_std
__global__ void k_bnstats(const float* __restrict__ h, float* __restrict__ mv) {
    __shared__ float s1[128], s2[128];
    int j = blockIdx.x, t = threadIdx.x;
    float v = h[(size_t)t * 512 + j];
    s1[t] = v; s2[t] = v * v;
    __syncthreads();
    for (int o = 64; o > 0; o >>= 1) {
        if (t < o) { s1[t] += s1[t + o]; s2[t] += s2[t + o]; }
        __syncthreads();
    }
    if (t == 0) {
        float m = s1[0] * (1.f / 128.f);
        float var = s2[0] * (1.f / 128.f) - m * m;
        mv[j] = m;
        mv[512 + j] = rsqrtf(var + 1e-5f);
    }
}

// ---------------- BN apply + relu + FC2 + log_softmax, one block per batch row
__global__ void k_head(const float* __restrict__ h, const float* __restrict__ mv,
                       const float* __restrict__ gamma, const float* __restrict__ beta,
                       const float* __restrict__ w2, const float* __restrict__ b2,
                       float* __restrict__ out) {
    __shared__ float hr[512];
    __shared__ float lg[16];
    int b = blockIdx.x, t = threadIdx.x;   // 64 threads
    for (int j = t; j < 512; j += 64) {
        float x = (h[(size_t)b * 512 + j] - mv[j]) * mv[512 + j] * gamma[j] + beta[j];
        hr[j] = fmaxf(x, 0.f);
    }
    __syncthreads();
    if (t < 10) {
        float a = b2[t];
        for (int j = 0; j < 512; ++j) a += hr[j] * w2[j * 10 + t];
        lg[t] = a;
    }
    __syncthreads();
    if (t == 0) {
        float mx = -1e30f;
        for (int q = 0; q < 10; ++q) mx = fmaxf(mx, lg[q]);
        float sum = 0.f;
        for (int q = 0; q < 10; ++q) sum += expf(lg[q] - mx);
        float ls = logf(sum) + mx;
        for (int q = 0; q < 10; ++q) out[b * 10 + q] = lg[q] - ls;
    }
}

extern "C" void kernel_launch(void* const* d_in, const int* in_sizes, int n_in,
                              void* d_out, int out_size, void* d_ws, size_t ws_size,
                              hipStream_t stream) {
    (void)in_sizes; (void)n_in; (void)out_size; (void)ws_size;
    const float* x      = (const float*)d_in[0];
    const int*   l0cols = (const int*)d_in[2];
    const float* l0vals = (const float*)d_in[3];
    const int*   l2cols = (const int*)d_in[5];
    const float* l2vals = (const float*)d_in[6];
    const int*   l4cols = (const int*)d_in[8];
    const float* l4vals = (const float*)d_in[9];
    const float* w1   = (const float*)d_in[10];
    const float* b1   = (const float*)d_in[11];
    const float* w2   = (const float*)d_in[12];
    const float* b2   = (const float*)d_in[13];
    const float* w3   = (const float*)d_in[14];
    const float* b3   = (const float*)d_in[15];
    const float* fc1w = (const float*)d_in[16];
    const float* fc1b = (const float*)d_in[17];
    const float* gam  = (const float*)d_in[18];
    const float* bet  = (const float*)d_in[19];
    const float* fc2w = (const float*)d_in[20];
    const float* fc2b = (const float*)d_in[21];
    float* out = (float*)d_out;

    const size_t S1 = 4096 * 128;    // layer-1 basis slot (floats)
    const size_t S2 = 1024 * 4096;   // layer-2 state size (floats); mirror slot = S2/2 dwords
    const size_t S3 = 256 * 8192;    // layer-3 state size (floats); mirror slot = S3/2 dwords

    float* ws = (float*)d_ws;
    float* basis1 = ws;                                  // 25 slots of S1 (layer-1, fp32)
    float* st2A   = ws + 25 * S1;                        // layer-2 state A (slab-major)
    float* st2B   = st2A + S2;                           // layer-2 state B
    unsigned* mir2 = (unsigned*)(st2B + S2);             // 5 slots of S2/2 dwords (also mir3 ring)
    float* acc3   = (float*)(mir2 + 5 * (S2 / 2));       // S3
    float* h      = acc3 + S3;                           // 65536
    float* mv     = h + 65536;                           // 1024
    unsigned short* wb2 = (unsigned short*)(mv + 1024);  // 51200 bf16
    unsigned short* wb3 = wb2 + 51200;                   // 102400 bf16
    float* acc2   = basis1;                              // alias: basis1 dead after proj1
    float* st3A   = st2A;                                // alias: layer-2 state dead
    float* st3B   = st2B;
    unsigned* mir3 = mir2;
    float* part   = basis1;                              // alias: acc2 dead by then

    k_packw<<<400, 256, 0, stream>>>(w2, w3, wb2, wb3);

    // ---------------- Layer 1: V=4096, C=128, full fp32 basis ----------------
    k_transpose_x<<<2048, 256, 0, stream>>>(x, basis1);
    for (int k = 1; k < 25; ++k) {
        const float* cur  = basis1 + (size_t)(k - 1) * S1;
        const float* prev = (k >= 2) ? basis1 + (size_t)(k - 2) * S1 : cur;
        float* next = basis1 + (size_t)k * S1;
        k_spmm1<<<1024, 256, 0, stream>>>(l0cols, l0vals, (const float2*)cur,
                                          (const float2*)prev, (float2*)next, k >= 2 ? 1 : 0);
    }
    // pool1 -> st2A (slab-major T0) + mir2 slot0
    k_proj1_pool<<<dim3(512, 2), 256, 0, stream>>>(basis1, w1, b1, st2A, mir2);

    // ---------------- Layer 2: V=1024, LDS-resident chunks of 5 ----------------
    for (int c = 0; c < 5; ++c) {
        int kk0 = (c == 0) ? 1 : 5 * c;
        int ns  = (c == 0) ? 4 : 5;
        k_chain2<<<1024, 256, 0, stream>>>(l2cols, l2vals, st2A, st2B, mir2, kk0, ns);
        k_proj_l2m<<<2048, 256, 0, stream>>>(mir2, S2 / 2, (const uint4*)wb2, acc2, 5 * c,
                                             c == 0 ? 1 : 0, b2);
    }
    k_relu_pool_m<<<4096, 256, 0, stream>>>(acc2, st3A, mir3);

    // ---------------- Layer 3: V=256, LDS-resident chunks of 5 ----------------
    for (int c = 0; c < 5; ++c) {
        int kk0 = (c == 0) ? 1 : 5 * c;
        int ns  = (c == 0) ? 4 : 5;
        k_chain3<<<2048, 256, 0, stream>>>(l4cols, l4vals, st3A, st3B, mir3, kk0, ns);
        k_proj_l3m<<<512, 256, 0, stream>>>(mir3, S3 / 2, (const uint4*)wb3, acc3, 5 * c,
                                            c == 0 ? 1 : 0, b3, c == 4 ? 1 : 0);
    }

    // ---------------- FC1 + BN + FC2 + log_softmax ----------------
    k_fc1_part<<<2048, 256, 0, stream>>>(acc3, fc1w, part);
    k_fc1_red<<<256, 256, 0, stream>>>(part, fc1b, h);
    k_bnstats<<<512, 128, 0, stream>>>(h, mv);
    k_head<<<128, 64, 0, stream>>>(h, mv, gam, bet, fc2w, fc2b, out);
}

// Round 13
// 919.729 us; speedup vs baseline: 1.2569x; 1.2569x over previous
//
#include <hip/hip_runtime.h>

#define B_ 128
#define K_ 25
#define DEG_ 16

#define R4(X) X(0) X(1) X(2) X(3)

typedef __attribute__((ext_vector_type(4))) float f32x4;
typedef __attribute__((ext_vector_type(8))) short bf16x8;

__device__ __forceinline__ float4 f4ma(float t, float4 w, float4 a) {
    a.x = fmaf(t, w.x, a.x); a.y = fmaf(t, w.y, a.y);
    a.z = fmaf(t, w.z, a.z); a.w = fmaf(t, w.w, a.w);
    return a;
}
__device__ __forceinline__ float4 f4max(float4 a, float4 b) {
    return make_float4(fmaxf(a.x, b.x), fmaxf(a.y, b.y), fmaxf(a.z, b.z), fmaxf(a.w, b.w));
}
__device__ __forceinline__ float4 f4add(float4 a, float4 b) {
    return make_float4(a.x + b.x, a.y + b.y, a.z + b.z, a.w + b.w);
}
// bf16 pack (RTNE)
__device__ __forceinline__ unsigned f2bfu(float f) {
    unsigned u = __float_as_uint(f);
    return (u + 0x7FFFu + ((u >> 16) & 1u)) >> 16;
}
__device__ __forceinline__ unsigned packbf(float e, float o) { return f2bfu(e) | (f2bfu(o) << 16); }

__device__ __forceinline__ bf16x8 u2b(uint4 u) {
    union { uint4 u4; bf16x8 b8; } c; c.u4 = u; return c.b8;
}
__device__ __forceinline__ f32x4 mfma_bf(uint4 a, uint4 b, f32x4 c) {
    return __builtin_amdgcn_mfma_f32_16x16x32_bf16(u2b(a), u2b(b), c, 0, 0, 0);
}

// ---------------- transpose x: (B=128, N=4096) -> x0 (4096, 128)
__global__ __launch_bounds__(256) void k_transpose_x(const float* __restrict__ x, float* __restrict__ x0) {
    int i = blockIdx.x * 256 + threadIdx.x;   // i = v*128 + b
    int v = i >> 7, b = i & 127;
    x0[i] = x[(b << 12) + v];
}

// ---------------- prepack W2/W3 -> bf16 [k][fo][fi]
__global__ __launch_bounds__(256) void k_packw(const float* __restrict__ w2, const float* __restrict__ w3,
        unsigned short* __restrict__ wb2, unsigned short* __restrict__ wb3) {
    int i = blockIdx.x * 256 + threadIdx.x;
    if (i < 51200) {        // 25*64*32
        int k = i >> 11, rem = i & 2047, fo = rem >> 5, fi = rem & 31;
        wb2[i] = (unsigned short)f2bfu(w2[(size_t)(fi * K_ + k) * 64 + fo]);
    }
    if (i < 102400) {       // 25*64*64
        int k = i >> 12, rem = i & 4095, fo = rem >> 6, fi = rem & 63;
        wb3[i] = (unsigned short)f2bfu(w3[(size_t)(fi * K_ + k) * 64 + fo]);
    }
}

// ---------------- layer-1 SpMM: 32 lanes per row (float4), 2 rows per wave, 2 accumulators
__global__ __launch_bounds__(256) void k_spmm1(const int* __restrict__ cols, const float* __restrict__ vals,
        const float4* __restrict__ cur, const float4* __restrict__ prev,
        float4* __restrict__ next, int two) {
    int t = blockIdx.x * 256 + threadIdx.x;   // 131072 threads
    int v = t >> 5, lane = t & 31;
    int base = v * DEG_;
    float4 s0 = make_float4(0.f, 0.f, 0.f, 0.f), s1 = s0;
#pragma unroll
    for (int d = 0; d < 8; ++d) {
        s0 = f4ma(vals[base + d],     cur[((size_t)cols[base + d] << 5) + lane], s0);
        s1 = f4ma(vals[base + 8 + d], cur[((size_t)cols[base + 8 + d] << 5) + lane], s1);
    }
    float4 s = f4add(s0, s1);
    size_t idx = ((size_t)v << 5) + lane;
    if (two) {
        float4 p = prev[idx];
        s.x = 2.f * s.x - p.x; s.y = 2.f * s.y - p.y;
        s.z = 2.f * s.z - p.z; s.w = 2.f * s.w - p.w;
    }
    next[idx] = s;
}

// ---------------- SpMM (layers 2/3) + packed-bf16 mirror write; 4 accumulators
template<int LOGC4>
__global__ __launch_bounds__(256) void k_spmm4(const int* __restrict__ cols, const float* __restrict__ vals,
                        const float4* __restrict__ cur, const float4* __restrict__ prev,
                        float4* __restrict__ next, unsigned* __restrict__ mir, int two) {
    constexpr int LOGW4 = LOGC4 - 3;
    int xcd = blockIdx.x & 7, q = blockIdx.x >> 3;
    int tid = q * 256 + threadIdx.x;
    int v = __builtin_amdgcn_readfirstlane(tid >> LOGW4);
    int c4 = (xcd << LOGW4) + (tid & ((1 << LOGW4) - 1));
    int base = v * DEG_;
    float4 s0 = make_float4(0.f, 0.f, 0.f, 0.f), s1 = s0, s2 = s0, s3 = s0;
#pragma unroll
    for (int d = 0; d < 4; ++d) {
        s0 = f4ma(vals[base + d],      cur[((size_t)cols[base + d] << LOGC4) + c4], s0);
        s1 = f4ma(vals[base + 4 + d],  cur[((size_t)cols[base + 4 + d] << LOGC4) + c4], s1);
        s2 = f4ma(vals[base + 8 + d],  cur[((size_t)cols[base + 8 + d] << LOGC4) + c4], s2);
        s3 = f4ma(vals[base + 12 + d], cur[((size_t)cols[base + 12 + d] << LOGC4) + c4], s3);
    }
    float4 s = f4add(f4add(s0, s1), f4add(s2, s3));
    size_t idx = ((size_t)v << LOGC4) + c4;
    if (two) {
        float4 p = prev[idx];
        s.x = 2.f * s.x - p.x; s.y = 2.f * s.y - p.y;
        s.z = 2.f * s.z - p.z; s.w = 2.f * s.w - p.w;
    }
    next[idx] = s;
    float tx = __shfl_down(s.x, 32), ty = __shfl_down(s.y, 32),
          tz = __shfl_down(s.z, 32), tw = __shfl_down(s.w, 32);
    if ((threadIdx.x & 63) < 32) {
        int c = c4 << 2;
        int fi2 = c >> 8, b0 = c & 127;
        uint4 m = make_uint4(packbf(s.x, tx), packbf(s.y, ty), packbf(s.z, tz), packbf(s.w, tw));
        *(uint4*)(mir + ((size_t)v << (LOGC4 + 1)) + ((size_t)fi2 << 7) + b0) = m;
    }
}

// ---------------- layer 1 projection (Fin=1, Fout=32) + bias + relu + pool4 (+ bf16 mirror)
__global__ __launch_bounds__(256) void k_proj1_pool(const float* __restrict__ basis,
        const float* __restrict__ W1, const float* __restrict__ b1, float* __restrict__ pool1,
        unsigned* __restrict__ mir) {
    int half = blockIdx.y;
    int i = blockIdx.x * 256 + threadIdx.x;   // i = g*128 + b
    int g = i >> 7, b = i & 127;
    const float* wbase = W1 + half * 16;
#define P1_DM(j) float4 M##j = make_float4(-1e30f, -1e30f, -1e30f, -1e30f);
    R4(P1_DM)
#undef P1_DM
    for (int r = 0; r < 4; ++r) {
        const float* bp = basis + (((size_t)(4 * g + r) << 7) + b);
#define P1_DC(j) float4 C##j = make_float4(0.f, 0.f, 0.f, 0.f);
        R4(P1_DC)
#undef P1_DC
#pragma unroll 5
        for (int k = 0; k < K_; ++k) {
            float tv = bp[(size_t)k * 524288];
            const float4* w = (const float4*)(wbase + k * 32);
#define P1_FM(j) C##j = f4ma(tv, w[j], C##j);
            R4(P1_FM)
#undef P1_FM
        }
#define P1_MX(j) M##j = f4max(M##j, C##j);
        R4(P1_MX)
#undef P1_MX
    }
    float* op = pool1 + ((size_t)g << 12) + ((size_t)half << 11) + b;
    unsigned* mp = mir + ((size_t)g << 11) + ((size_t)half << 10) + b;
    const float* bb = b1 + half * 16;
#define P1_ST(j) { \
    float e0 = fmaxf(M##j.x + bb[4*j+0], 0.f); \
    float o0 = fmaxf(M##j.y + bb[4*j+1], 0.f); \
    float e1 = fmaxf(M##j.z + bb[4*j+2], 0.f); \
    float o1 = fmaxf(M##j.w + bb[4*j+3], 0.f); \
    op[(4*j+0)*128] = e0; op[(4*j+1)*128] = o0; \
    op[(4*j+2)*128] = e1; op[(4*j+3)*128] = o1; \
    mp[(2*j+0)*128] = packbf(e0, o0); \
    mp[(2*j+1)*128] = packbf(e1, o1); }
    R4(P1_ST)
#undef P1_ST
}

// ---------------- layer-2 chunk projection via MFMA: one wave = 16 b x 64 fo, K=5kk*32fi
__global__ __launch_bounds__(256) void k_proj_l2m(const unsigned* __restrict__ mir, size_t slotH,
        const uint4* __restrict__ wb, float* __restrict__ acc, int k0, int init,
        const float* __restrict__ bias) {
    int wid = blockIdx.x * 4 + (threadIdx.x >> 6);   // 8192 waves
    int lane = threadIdx.x & 63;
    int lm = lane & 15, lg = lane >> 4;
    int v = wid >> 3, b0 = (wid & 7) << 4;
    float* ap = acc + ((size_t)v << 13) + b0 + (lg << 2);
    f32x4 C0, C1, C2, C3;
    if (init) {
        float q0 = bias[lm], q1 = bias[16 + lm], q2 = bias[32 + lm], q3 = bias[48 + lm];
        C0 = f32x4{q0, q0, q0, q0}; C1 = f32x4{q1, q1, q1, q1};
        C2 = f32x4{q2, q2, q2, q2}; C3 = f32x4{q3, q3, q3, q3};
    } else {
        C0 = *(const f32x4*)(ap + (size_t)lm * 128);
        C1 = *(const f32x4*)(ap + (size_t)(16 + lm) * 128);
        C2 = *(const f32x4*)(ap + (size_t)(32 + lm) * 128);
        C3 = *(const f32x4*)(ap + (size_t)(48 + lm) * 128);
    }
    const unsigned* mp0 = mir + ((size_t)v << 11) + (lg << 9) + b0 + lm;
#pragma unroll
    for (int kk = 0; kk < 5; ++kk) {
        const unsigned* mp = mp0 + (size_t)kk * slotH;
        uint4 a = make_uint4(mp[0], mp[128], mp[256], mp[384]);
        int kb = (k0 + kk) << 6;
        uint4 w0 = wb[(kb + lm) * 4 + lg];
        uint4 w1 = wb[(kb + 16 + lm) * 4 + lg];
        uint4 w2 = wb[(kb + 32 + lm) * 4 + lg];
        uint4 w3 = wb[(kb + 48 + lm) * 4 + lg];
        C0 = mfma_bf(a, w0, C0);
        C1 = mfma_bf(a, w1, C1);
        C2 = mfma_bf(a, w2, C2);
        C3 = mfma_bf(a, w3, C3);
    }
    *(f32x4*)(ap + (size_t)lm * 128) = C0;
    *(f32x4*)(ap + (size_t)(16 + lm) * 128) = C1;
    *(f32x4*)(ap + (size_t)(32 + lm) * 128) = C2;
    *(f32x4*)(ap + (size_t)(48 + lm) * 128) = C3;
}

// ---------------- layer-3 chunk projection via MFMA: Fin=64 -> 2 K-steps per kk
__global__ __launch_bounds__(256) void k_proj_l3m(const unsigned* __restrict__ mir, size_t slotH,
        const uint4* __restrict__ wb, float* __restrict__ acc, int k0, int init,
        const float* __restrict__ bias, int finalrelu) {
    int wid = blockIdx.x * 4 + (threadIdx.x >> 6);   // 2048 waves
    int lane = threadIdx.x & 63;
    int lm = lane & 15, lg = lane >> 4;
    int v = wid >> 3, b0 = (wid & 7) << 4;
    float* ap = acc + ((size_t)v << 13) + b0 + (lg << 2);
    f32x4 C0, C1, C2, C3;
    if (init) {
        float q0 = bias[lm], q1 = bias[16 + lm], q2 = bias[32 + lm], q3 = bias[48 + lm];
        C0 = f32x4{q0, q0, q0, q0}; C1 = f32x4{q1, q1, q1, q1};
        C2 = f32x4{q2, q2, q2, q2}; C3 = f32x4{q3, q3, q3, q3};
    } else {
        C0 = *(const f32x4*)(ap + (size_t)lm * 128);
        C1 = *(const f32x4*)(ap + (size_t)(16 + lm) * 128);
        C2 = *(const f32x4*)(ap + (size_t)(32 + lm) * 128);
        C3 = *(const f32x4*)(ap + (size_t)(48 + lm) * 128);
    }
    const unsigned* mp0 = mir + ((size_t)v << 12) + b0 + lm;
#pragma unroll
    for (int kk = 0; kk < 5; ++kk) {
        const unsigned* mp = mp0 + (size_t)kk * slotH;
        int kb = (k0 + kk) << 6;
#pragma unroll
        for (int ks = 0; ks < 2; ++ks) {
            const unsigned* mk = mp + (size_t)((ks << 4) + (lg << 2)) * 128;
            uint4 a = make_uint4(mk[0], mk[128], mk[256], mk[384]);
            int wof = (ks << 2) + lg;
            uint4 w0 = wb[(kb + lm) * 8 + wof];
            uint4 w1 = wb[(kb + 16 + lm) * 8 + wof];
            uint4 w2 = wb[(kb + 32 + lm) * 8 + wof];
            uint4 w3 = wb[(kb + 48 + lm) * 8 + wof];
            C0 = mfma_bf(a, w0, C0);
            C1 = mfma_bf(a, w1, C1);
            C2 = mfma_bf(a, w2, C2);
            C3 = mfma_bf(a, w3, C3);
        }
    }
    if (finalrelu) {
#pragma unroll
        for (int r = 0; r < 4; ++r) {
            C0[r] = fmaxf(C0[r], 0.f); C1[r] = fmaxf(C1[r], 0.f);
            C2[r] = fmaxf(C2[r], 0.f); C3[r] = fmaxf(C3[r], 0.f);
        }
    }
    *(f32x4*)(ap + (size_t)lm * 128) = C0;
    *(f32x4*)(ap + (size_t)(16 + lm) * 128) = C1;
    *(f32x4*)(ap + (size_t)(32 + lm) * 128) = C2;
    *(f32x4*)(ap + (size_t)(48 + lm) * 128) = C3;
}

// ---------------- relu + pool4 + bf16 mirror (layer2 acc -> pool2 + mirror slot0)
__global__ __launch_bounds__(256) void k_relu_pool_m(const float* __restrict__ acc,
        float* __restrict__ pool, unsigned* __restrict__ mir) {
    int i = blockIdx.x * 256 + threadIdx.x;   // g*4096 + fi2*128 + b, total 1,048,576
    int g = i >> 12, fi2 = (i >> 7) & 31, b = i & 127;
    const float* ap = acc + (((size_t)g << 2) << 13) + (fi2 << 8) + b;
    float me = 0.f, mo = 0.f;
#pragma unroll
    for (int r = 0; r < 4; ++r) {
        me = fmaxf(me, ap[0]); mo = fmaxf(mo, ap[128]);
        ap += 8192;
    }
    size_t po = ((size_t)g << 13) + (fi2 << 8) + b;
    pool[po] = me; pool[po + 128] = mo;
    mir[i] = packbf(me, mo);
}

// ---------------- FC1 partials: rowsplit 64, 8 b's per thread, 2048 blocks
__global__ __launch_bounds__(256) void k_fc1_part(const float* __restrict__ t3, const float* __restrict__ w,
                           float* __restrict__ part) {
    int blk = blockIdx.x;
    int bg = blk >> 7;
    int rs = (blk >> 1) & 63;
    int j = ((blk & 1) << 8) + threadIdx.x;
    int b0 = bg << 3;
    float a0=0.f,a1=0.f,a2=0.f,a3=0.f,a4=0.f,a5=0.f,a6=0.f,a7=0.f;
    int r0 = rs << 8;
#pragma unroll 4
    for (int row = r0; row < r0 + 256; ++row) {
        float wv = w[((size_t)row << 9) + j];
        const float4* tp = (const float4*)(t3 + ((size_t)row << 7) + b0);
        float4 t0 = tp[0], t1 = tp[1];
        a0 = fmaf(t0.x, wv, a0);
        a1 = fmaf(t0.y, wv, a1);
        a2 = fmaf(t0.z, wv, a2);
        a3 = fmaf(t0.w, wv, a3);
        a4 = fmaf(t1.x, wv, a4);
        a5 = fmaf(t1.y, wv, a5);
        a6 = fmaf(t1.z, wv, a6);
        a7 = fmaf(t1.w, wv, a7);
    }
    float* pp = part + (((size_t)(rs << 7) + b0) << 9) + j;
    pp[0*512]=a0; pp[1*512]=a1; pp[2*512]=a2; pp[3*512]=a3;
    pp[4*512]=a4; pp[5*512]=a5; pp[6*512]=a6; pp[7*512]=a7;
}

__global__ __launch_bounds__(256) void k_fc1_red(const float* __restrict__ part, const float* __restrict__ bias,
                          float* __restrict__ h) {
    int i = blockIdx.x * 256 + threadIdx.x;   // i = b*512 + j
    float a = bias[i & 511];
#pragma unroll 8
    for (int rs = 0; rs < 64; ++rs) a += part[((size_t)rs << 16) + i];
    h[i] = a;
}

// ---------------- batchnorm stats over batch (biased var), store mean | inv_std
__global__ void k_bnstats(const float* __restrict__ h, float* __restrict__ mv) {
    __shared__ float s1[128], s2[128];
    int j = blockIdx.x, t = threadIdx.x;
    float v = h[(size_t)t * 512 + j];
    s1[t] = v; s2[t] = v * v;
    __syncthreads();
    for (int o = 64; o > 0; o >>= 1) {
        if (t < o) { s1[t] += s1[t + o]; s2[t] += s2[t + o]; }
        __syncthreads();
    }
    if (t == 0) {
        float m = s1[0] * (1.f / 128.f);
        float var = s2[0] * (1.f / 128.f) - m * m;
        mv[j] = m;
        mv[512 + j] = rsqrtf(var + 1e-5f);
    }
}

// ---------------- BN apply + relu + FC2 + log_softmax, one block per batch row
__global__ void k_head(const float* __restrict__ h, const float* __restrict__ mv,
                       const float* __restrict__ gamma, const float* __restrict__ beta,
                       const float* __restrict__ w2, const float* __restrict__ b2,
                       float* __restrict__ out) {
    __shared__ float hr[512];
    __shared__ float lg[16];
    int b = blockIdx.x, t = threadIdx.x;   // 64 threads
    for (int j = t; j < 512; j += 64) {
        float x = (h[(size_t)b * 512 + j] - mv[j]) * mv[512 + j] * gamma[j] + beta[j];
        hr[j] = fmaxf(x, 0.f);
    }
    __syncthreads();
    if (t < 10) {
        float a = b2[t];
        for (int j = 0; j < 512; ++j) a += hr[j] * w2[j * 10 + t];
        lg[t] = a;
    }
    __syncthreads();
    if (t == 0) {
        float mx = -1e30f;
        for (int q = 0; q < 10; ++q) mx = fmaxf(mx, lg[q]);
        float sum = 0.f;
        for (int q = 0; q < 10; ++q) sum += expf(lg[q] - mx);
        float ls = logf(sum) + mx;
        for (int q = 0; q < 10; ++q) out[b * 10 + q] = lg[q] - ls;
    }
}

extern "C" void kernel_launch(void* const* d_in, const int* in_sizes, int n_in,
                              void* d_out, int out_size, void* d_ws, size_t ws_size,
                              hipStream_t stream) {
    (void)in_sizes; (void)n_in; (void)out_size; (void)ws_size;
    const float* x      = (const float*)d_in[0];
    const int*   l0cols = (const int*)d_in[2];
    const float* l0vals = (const float*)d_in[3];
    const int*   l2cols = (const int*)d_in[5];
    const float* l2vals = (const float*)d_in[6];
    const int*   l4cols = (const int*)d_in[8];
    const float* l4vals = (const float*)d_in[9];
    const float* w1   = (const float*)d_in[10];
    const float* b1   = (const float*)d_in[11];
    const float* w2   = (const float*)d_in[12];
    const float* b2   = (const float*)d_in[13];
    const float* w3   = (const float*)d_in[14];
    const float* b3   = (const float*)d_in[15];
    const float* fc1w = (const float*)d_in[16];
    const float* fc1b = (const float*)d_in[17];
    const float* gam  = (const float*)d_in[18];
    const float* bet  = (const float*)d_in[19];
    const float* fc2w = (const float*)d_in[20];
    const float* fc2b = (const float*)d_in[21];
    float* out = (float*)d_out;

    const size_t S1 = 4096 * 128;    // layer-1 basis slot (floats)
    const size_t S2 = 1024 * 4096;   // layer-2 slot (floats); mirror slot = S2/2 dwords
    const size_t S3 = 256 * 8192;    // layer-3 slot (floats); mirror slot = S3/2 dwords
    const int CKP = 5;               // uniform chunks; mirror stays L3-hot

    float* ws = (float*)d_ws;
    float* basis1 = ws;                                  // 25 slots of S1 (layer-1, fp32)
    float* ring2f = ws + 25 * S1;                        // 3 slots S2 (fp32 recursion ring)
    unsigned* mir2 = (unsigned*)(ring2f + 3 * S2);       // CKP slots of S2/2 dwords; also mir3
    float* tailp  = (float*)(mir2 + (size_t)CKP * (S2 / 2));
    float* h      = tailp;                               // 65536
    float* mv     = h + 65536;                           // 1024
    unsigned short* wb2 = (unsigned short*)(mv + 1024);  // 51200 bf16
    unsigned short* wb3 = wb2 + 51200;                   // 102400 bf16
    float* acc2   = basis1;                              // alias: basis1 dead after proj1
    float* ring3f = ring2f;                              // 3 slots S3; slot0 = pool2
    float* acc3   = ring2f + 3 * S3;                     // 4*S3 <= 3*S2
    unsigned* mir3 = mir2;                               // CKP*S3/2 <= CKP*S2/2
    float* part   = basis1;                              // alias: acc2 dead by then

    k_packw<<<400, 256, 0, stream>>>(w2, w3, wb2, wb3);

    // ---------------- Layer 1: V=4096, C=128, full fp32 basis ----------------
    k_transpose_x<<<2048, 256, 0, stream>>>(x, basis1);
    for (int k = 1; k < 25; ++k) {
        const float* cur  = basis1 + (size_t)(k - 1) * S1;
        const float* prev = (k >= 2) ? basis1 + (size_t)(k - 2) * S1 : cur;
        float* next = basis1 + (size_t)k * S1;
        k_spmm1<<<512, 256, 0, stream>>>(l0cols, l0vals, (const float4*)cur,
                                         (const float4*)prev, (float4*)next, k >= 2 ? 1 : 0);
    }
    // pool1 -> ring2f slot0 (fp32, x0 for recursion) + mir2 slot0 (bf16, for proj)
    k_proj1_pool<<<dim3(512, 2), 256, 0, stream>>>(basis1, w1, b1, ring2f, mir2);

    // ---------------- Layer 2: V=1024, C=4096 ----------------
    {
        int cs = 0;
        for (int k = 0; k < 25; ++k) {
            if (k >= 1) {
                const float* cur  = ring2f + (size_t)((k - 1) % 3) * S2;
                const float* prev = ring2f + (size_t)((k >= 2 ? k - 2 : 0) % 3) * S2;
                float* next = ring2f + (size_t)(k % 3) * S2;
                unsigned* mirp = mir2 + (size_t)(k % CKP) * (S2 / 2);
                k_spmm4<10><<<4096, 256, 0, stream>>>(l2cols, l2vals, (const float4*)cur,
                                                      (const float4*)prev, (float4*)next,
                                                      mirp, k >= 2 ? 1 : 0);
            }
            if (k - cs + 1 == CKP) {
                k_proj_l2m<<<2048, 256, 0, stream>>>(mir2, S2 / 2, (const uint4*)wb2, acc2, cs,
                                                     cs == 0 ? 1 : 0, b2);
                cs = k + 1;
            }
        }
    }
    k_relu_pool_m<<<4096, 256, 0, stream>>>(acc2, ring3f /*pool2 = slot0*/, mir3 /*slot0*/);

    // ---------------- Layer 3: V=256, C=8192 ----------------
    {
        int cs = 0;
        for (int k = 0; k < 25; ++k) {
            if (k >= 1) {
                const float* cur  = ring3f + (size_t)((k - 1) % 3) * S3;
                const float* prev = ring3f + (size_t)((k >= 2 ? k - 2 : 0) % 3) * S3;
                float* next = ring3f + (size_t)(k % 3) * S3;
                unsigned* mirp = mir3 + (size_t)(k % CKP) * (S3 / 2);
                k_spmm4<11><<<2048, 256, 0, stream>>>(l4cols, l4vals, (const float4*)cur,
                                                      (const float4*)prev, (float4*)next,
                                                      mirp, k >= 2 ? 1 : 0);
            }
            if (k - cs + 1 == CKP) {
                k_proj_l3m<<<512, 256, 0, stream>>>(mir3, S3 / 2, (const uint4*)wb3, acc3, cs,
                                                    cs == 0 ? 1 : 0, b3, cs == 20 ? 1 : 0);
                cs = k + 1;
            }
        }
    }

    // ---------------- FC1 + BN + FC2 + log_softmax ----------------
    k_fc1_part<<<2048, 256, 0, stream>>>(acc3, fc1w, part);
    k_fc1_red<<<256, 256, 0, stream>>>(part, fc1b, h);
    k_bnstats<<<512, 128, 0, stream>>>(h, mv);
    k_head<<<128, 64, 0, stream>>>(h, mv, gam, bet, fc2w, fc2b, out);
}

// Round 14
// 808.233 us; speedup vs baseline: 1.4303x; 1.1379x over previous
//
#include <hip/hip_runtime.h>

#define B_ 128
#define K_ 25
#define DEG_ 16

#define R4(X) X(0) X(1) X(2) X(3)

typedef __attribute__((ext_vector_type(4))) float f32x4;
typedef __attribute__((ext_vector_type(8))) short bf16x8;

__device__ __forceinline__ float4 f4ma(float t, float4 w, float4 a) {
    a.x = fmaf(t, w.x, a.x); a.y = fmaf(t, w.y, a.y);
    a.z = fmaf(t, w.z, a.z); a.w = fmaf(t, w.w, a.w);
    return a;
}
__device__ __forceinline__ float4 f4max(float4 a, float4 b) {
    return make_float4(fmaxf(a.x, b.x), fmaxf(a.y, b.y), fmaxf(a.z, b.z), fmaxf(a.w, b.w));
}
__device__ __forceinline__ float4 f4add(float4 a, float4 b) {
    return make_float4(a.x + b.x, a.y + b.y, a.z + b.z, a.w + b.w);
}
__device__ __forceinline__ float4 f4sub2(float4 s, float4 p) {
    return make_float4(2.f * s.x - p.x, 2.f * s.y - p.y, 2.f * s.z - p.z, 2.f * s.w - p.w);
}
// bf16 pack (RTNE)
__device__ __forceinline__ unsigned f2bfu(float f) {
    unsigned u = __float_as_uint(f);
    return (u + 0x7FFFu + ((u >> 16) & 1u)) >> 16;
}
__device__ __forceinline__ unsigned packbf(float e, float o) { return f2bfu(e) | (f2bfu(o) << 16); }
// mirror dword -> even/odd fi floats
__device__ __forceinline__ float4 mevens(uint4 m) {
    return make_float4(__uint_as_float(m.x << 16), __uint_as_float(m.y << 16),
                       __uint_as_float(m.z << 16), __uint_as_float(m.w << 16));
}
__device__ __forceinline__ float4 modds(uint4 m) {
    return make_float4(__uint_as_float(m.x & 0xFFFF0000u), __uint_as_float(m.y & 0xFFFF0000u),
                       __uint_as_float(m.z & 0xFFFF0000u), __uint_as_float(m.w & 0xFFFF0000u));
}

__device__ __forceinline__ bf16x8 u2b(uint4 u) {
    union { uint4 u4; bf16x8 b8; } c; c.u4 = u; return c.b8;
}
__device__ __forceinline__ f32x4 mfma_bf(uint4 a, uint4 b, f32x4 c) {
    return __builtin_amdgcn_mfma_f32_16x16x32_bf16(u2b(a), u2b(b), c, 0, 0, 0);
}

// ---------------- transpose x: (B=128, N=4096) -> x0 (4096, 128)
__global__ __launch_bounds__(256) void k_transpose_x(const float* __restrict__ x, float* __restrict__ x0) {
    int i = blockIdx.x * 256 + threadIdx.x;   // i = v*128 + b
    int v = i >> 7, b = i & 127;
    x0[i] = x[(b << 12) + v];
}

// ---------------- prepack W2/W3 -> bf16 [k][fo][fi]
__global__ __launch_bounds__(256) void k_packw(const float* __restrict__ w2, const float* __restrict__ w3,
        unsigned short* __restrict__ wb2, unsigned short* __restrict__ wb3) {
    int i = blockIdx.x * 256 + threadIdx.x;
    if (i < 51200) {        // 25*64*32
        int k = i >> 11, rem = i & 2047, fo = rem >> 5, fi = rem & 31;
        wb2[i] = (unsigned short)f2bfu(w2[(size_t)(fi * K_ + k) * 64 + fo]);
    }
    if (i < 102400) {       // 25*64*64
        int k = i >> 12, rem = i & 4095, fo = rem >> 6, fi = rem & 63;
        wb3[i] = (unsigned short)f2bfu(w3[(size_t)(fi * K_ + k) * 64 + fo]);
    }
}

// ---------------- layer-1 SpMM: 32 lanes per row (float4), fp32 (exact early chain)
__global__ __launch_bounds__(256) void k_spmm1(const int* __restrict__ cols, const float* __restrict__ vals,
        const float4* __restrict__ cur, const float4* __restrict__ prev,
        float4* __restrict__ next, int two) {
    int t = blockIdx.x * 256 + threadIdx.x;   // 131072 threads
    int v = t >> 5, lane = t & 31;
    int base = v * DEG_;
    float4 s0 = make_float4(0.f, 0.f, 0.f, 0.f), s1 = s0;
#pragma unroll
    for (int d = 0; d < 8; ++d) {
        s0 = f4ma(vals[base + d],     cur[((size_t)cols[base + d] << 5) + lane], s0);
        s1 = f4ma(vals[base + 8 + d], cur[((size_t)cols[base + 8 + d] << 5) + lane], s1);
    }
    float4 s = f4add(s0, s1);
    size_t idx = ((size_t)v << 5) + lane;
    if (two) {
        float4 p = prev[idx];
        s.x = 2.f * s.x - p.x; s.y = 2.f * s.y - p.y;
        s.z = 2.f * s.z - p.z; s.w = 2.f * s.w - p.w;
    }
    next[idx] = s;
}

// ---------------- SpMM (layers 2/3) gathering from the bf16 mirror; fp32 prev/next in-place
// thread owns (v, fi2 pair, 4 b). LOGF2: 4 (layer2, fi2 in [0,16)) / 5 (layer3, [0,32)).
// mirror dword = v*(FI2*128) + fi2*128 + b;  state float = v*(FI2*256) + fi2*256 + [0|128] + b.
template<int LOGF2>
__global__ __launch_bounds__(256) void k_spmm4m(const int* __restrict__ cols, const float* __restrict__ vals,
        const unsigned* __restrict__ mirPrev, float* __restrict__ st,
        unsigned* __restrict__ mirOut, int two) {
    constexpr int SL = LOGF2 + 2;                 // threads per (v, slab)
    constexpr int MSTR = 1 << (LOGF2 + 7);        // mirror v-stride (dwords)
    int xcd = blockIdx.x & 7, q = blockIdx.x >> 3;
    int v = __builtin_amdgcn_readfirstlane((q << (8 - SL)) + (threadIdx.x >> SL));
    int l = threadIdx.x & ((1 << SL) - 1);
    int cc = (xcd << SL) + l;
    int fi2 = cc >> 5, b0 = (cc & 31) << 2;
    int base = v * DEG_;
    int moff = (fi2 << 7) + b0;
    float4 eA = make_float4(0.f, 0.f, 0.f, 0.f), eB = eA, oA = eA, oB = eA;
#pragma unroll
    for (int d = 0; d < 8; ++d) {
        {
            float w = vals[base + d];
            uint4 m = *(const uint4*)(mirPrev + (size_t)cols[base + d] * MSTR + moff);
            eA = f4ma(w, mevens(m), eA); oA = f4ma(w, modds(m), oA);
        }
        {
            float w = vals[base + 8 + d];
            uint4 m = *(const uint4*)(mirPrev + (size_t)cols[base + 8 + d] * MSTR + moff);
            eB = f4ma(w, mevens(m), eB); oB = f4ma(w, modds(m), oB);
        }
    }
    float4 e = f4add(eA, eB), o = f4add(oA, oB);
    size_t sidx = ((size_t)v << (LOGF2 + 8)) + (fi2 << 8) + b0;
    if (two) {
        float4 pe = *(const float4*)(st + sidx), po = *(const float4*)(st + sidx + 128);
        e = f4sub2(e, pe); o = f4sub2(o, po);
    }
    *(float4*)(st + sidx) = e;
    *(float4*)(st + sidx + 128) = o;
    *(uint4*)(mirOut + (size_t)v * MSTR + moff) =
        make_uint4(packbf(e.x, o.x), packbf(e.y, o.y), packbf(e.z, o.z), packbf(e.w, o.w));
}

// ---------------- layer 1 projection (Fin=1, Fout=32) + bias + relu + pool4 (+ bf16 mirror)
__global__ __launch_bounds__(256) void k_proj1_pool(const float* __restrict__ basis,
        const float* __restrict__ W1, const float* __restrict__ b1, float* __restrict__ pool1,
        unsigned* __restrict__ mir) {
    int half = blockIdx.y;
    int i = blockIdx.x * 256 + threadIdx.x;   // i = g*128 + b
    int g = i >> 7, b = i & 127;
    const float* wbase = W1 + half * 16;
#define P1_DM(j) float4 M##j = make_float4(-1e30f, -1e30f, -1e30f, -1e30f);
    R4(P1_DM)
#undef P1_DM
    for (int r = 0; r < 4; ++r) {
        const float* bp = basis + (((size_t)(4 * g + r) << 7) + b);
#define P1_DC(j) float4 C##j = make_float4(0.f, 0.f, 0.f, 0.f);
        R4(P1_DC)
#undef P1_DC
#pragma unroll 5
        for (int k = 0; k < K_; ++k) {
            float tv = bp[(size_t)k * 524288];
            const float4* w = (const float4*)(wbase + k * 32);
#define P1_FM(j) C##j = f4ma(tv, w[j], C##j);
            R4(P1_FM)
#undef P1_FM
        }
#define P1_MX(j) M##j = f4max(M##j, C##j);
        R4(P1_MX)
#undef P1_MX
    }
    float* op = pool1 + ((size_t)g << 12) + ((size_t)half << 11) + b;
    unsigned* mp = mir + ((size_t)g << 11) + ((size_t)half << 10) + b;
    const float* bb = b1 + half * 16;
#define P1_ST(j) { \
    float e0 = fmaxf(M##j.x + bb[4*j+0], 0.f); \
    float o0 = fmaxf(M##j.y + bb[4*j+1], 0.f); \
    float e1 = fmaxf(M##j.z + bb[4*j+2], 0.f); \
    float o1 = fmaxf(M##j.w + bb[4*j+3], 0.f); \
    op[(4*j+0)*128] = e0; op[(4*j+1)*128] = o0; \
    op[(4*j+2)*128] = e1; op[(4*j+3)*128] = o1; \
    mp[(2*j+0)*128] = packbf(e0, o0); \
    mp[(2*j+1)*128] = packbf(e1, o1); }
    R4(P1_ST)
#undef P1_ST
}

// ---------------- layer-2 chunk projection via MFMA: one wave = 16 b x 64 fo, K=5kk*32fi
__global__ __launch_bounds__(256) void k_proj_l2m(const unsigned* __restrict__ mir, size_t slotH,
        const uint4* __restrict__ wb, float* __restrict__ acc, int k0, int init,
        const float* __restrict__ bias) {
    int wid = blockIdx.x * 4 + (threadIdx.x >> 6);   // 8192 waves
    int lane = threadIdx.x & 63;
    int lm = lane & 15, lg = lane >> 4;
    int v = wid >> 3, b0 = (wid & 7) << 4;
    float* ap = acc + ((size_t)v << 13) + b0 + (lg << 2);
    f32x4 C0, C1, C2, C3;
    if (init) {
        float q0 = bias[lm], q1 = bias[16 + lm], q2 = bias[32 + lm], q3 = bias[48 + lm];
        C0 = f32x4{q0, q0, q0, q0}; C1 = f32x4{q1, q1, q1, q1};
        C2 = f32x4{q2, q2, q2, q2}; C3 = f32x4{q3, q3, q3, q3};
    } else {
        C0 = *(const f32x4*)(ap + (size_t)lm * 128);
        C1 = *(const f32x4*)(ap + (size_t)(16 + lm) * 128);
        C2 = *(const f32x4*)(ap + (size_t)(32 + lm) * 128);
        C3 = *(const f32x4*)(ap + (size_t)(48 + lm) * 128);
    }
    const unsigned* mp0 = mir + ((size_t)v << 11) + (lg << 9) + b0 + lm;
#pragma unroll
    for (int kk = 0; kk < 5; ++kk) {
        const unsigned* mp = mp0 + (size_t)kk * slotH;
        uint4 a = make_uint4(mp[0], mp[128], mp[256], mp[384]);
        int kb = (k0 + kk) << 6;
        uint4 w0 = wb[(kb + lm) * 4 + lg];
        uint4 w1 = wb[(kb + 16 + lm) * 4 + lg];
        uint4 w2 = wb[(kb + 32 + lm) * 4 + lg];
        uint4 w3 = wb[(kb + 48 + lm) * 4 + lg];
        C0 = mfma_bf(a, w0, C0);
        C1 = mfma_bf(a, w1, C1);
        C2 = mfma_bf(a, w2, C2);
        C3 = mfma_bf(a, w3, C3);
    }
    *(f32x4*)(ap + (size_t)lm * 128) = C0;
    *(f32x4*)(ap + (size_t)(16 + lm) * 128) = C1;
    *(f32x4*)(ap + (size_t)(32 + lm) * 128) = C2;
    *(f32x4*)(ap + (size_t)(48 + lm) * 128) = C3;
}

// ---------------- layer-3 chunk projection via MFMA: Fin=64 -> 2 K-steps per kk
__global__ __launch_bounds__(256) void k_proj_l3m(const unsigned* __restrict__ mir, size_t slotH,
        const uint4* __restrict__ wb, float* __restrict__ acc, int k0, int init,
        const float* __restrict__ bias, int finalrelu) {
    int wid = blockIdx.x * 4 + (threadIdx.x >> 6);   // 2048 waves
    int lane = threadIdx.x & 63;
    int lm = lane & 15, lg = lane >> 4;
    int v = wid >> 3, b0 = (wid & 7) << 4;
    float* ap = acc + ((size_t)v << 13) + b0 + (lg << 2);
    f32x4 C0, C1, C2, C3;
    if (init) {
        float q0 = bias[lm], q1 = bias[16 + lm], q2 = bias[32 + lm], q3 = bias[48 + lm];
        C0 = f32x4{q0, q0, q0, q0}; C1 = f32x4{q1, q1, q1, q1};
        C2 = f32x4{q2, q2, q2, q2}; C3 = f32x4{q3, q3, q3, q3};
    } else {
        C0 = *(const f32x4*)(ap + (size_t)lm * 128);
        C1 = *(const f32x4*)(ap + (size_t)(16 + lm) * 128);
        C2 = *(const f32x4*)(ap + (size_t)(32 + lm) * 128);
        C3 = *(const f32x4*)(ap + (size_t)(48 + lm) * 128);
    }
    const unsigned* mp0 = mir + ((size_t)v << 12) + b0 + lm;
#pragma unroll
    for (int kk = 0; kk < 5; ++kk) {
        const unsigned* mp = mp0 + (size_t)kk * slotH;
        int kb = (k0 + kk) << 6;
#pragma unroll
        for (int ks = 0; ks < 2; ++ks) {
            const unsigned* mk = mp + (size_t)((ks << 4) + (lg << 2)) * 128;
            uint4 a = make_uint4(mk[0], mk[128], mk[256], mk[384]);
            int wof = (ks << 2) + lg;
            uint4 w0 = wb[(kb + lm) * 8 + wof];
            uint4 w1 = wb[(kb + 16 + lm) * 8 + wof];
            uint4 w2 = wb[(kb + 32 + lm) * 8 + wof];
            uint4 w3 = wb[(kb + 48 + lm) * 8 + wof];
            C0 = mfma_bf(a, w0, C0);
            C1 = mfma_bf(a, w1, C1);
            C2 = mfma_bf(a, w2, C2);
            C3 = mfma_bf(a, w3, C3);
        }
    }
    if (finalrelu) {
#pragma unroll
        for (int r = 0; r < 4; ++r) {
            C0[r] = fmaxf(C0[r], 0.f); C1[r] = fmaxf(C1[r], 0.f);
            C2[r] = fmaxf(C2[r], 0.f); C3[r] = fmaxf(C3[r], 0.f);
        }
    }
    *(f32x4*)(ap + (size_t)lm * 128) = C0;
    *(f32x4*)(ap + (size_t)(16 + lm) * 128) = C1;
    *(f32x4*)(ap + (size_t)(32 + lm) * 128) = C2;
    *(f32x4*)(ap + (size_t)(48 + lm) * 128) = C3;
}

// ---------------- relu + pool4 + bf16 mirror (layer2 acc -> layer3 T0 state + mirror slot0)
__global__ __launch_bounds__(256) void k_relu_pool_m(const float* __restrict__ acc,
        float* __restrict__ pool, unsigned* __restrict__ mir) {
    int i = blockIdx.x * 256 + threadIdx.x;   // g*4096 + fi2*128 + b, total 1,048,576
    int g = i >> 12, fi2 = (i >> 7) & 31, b = i & 127;
    const float* ap = acc + (((size_t)g << 2) << 13) + (fi2 << 8) + b;
    float me = 0.f, mo = 0.f;
#pragma unroll
    for (int r = 0; r < 4; ++r) {
        me = fmaxf(me, ap[0]); mo = fmaxf(mo, ap[128]);
        ap += 8192;
    }
    size_t po = ((size_t)g << 13) + (fi2 << 8) + b;
    pool[po] = me; pool[po + 128] = mo;
    mir[i] = packbf(me, mo);
}

// ---------------- FC1 partials: rowsplit 64, 8 b's per thread, 2048 blocks
__global__ __launch_bounds__(256) void k_fc1_part(const float* __restrict__ t3, const float* __restrict__ w,
                           float* __restrict__ part) {
    int blk = blockIdx.x;
    int bg = blk >> 7;
    int rs = (blk >> 1) & 63;
    int j = ((blk & 1) << 8) + threadIdx.x;
    int b0 = bg << 3;
    float a0=0.f,a1=0.f,a2=0.f,a3=0.f,a4=0.f,a5=0.f,a6=0.f,a7=0.f;
    int r0 = rs << 8;
#pragma unroll 4
    for (int row = r0; row < r0 + 256; ++row) {
        float wv = w[((size_t)row << 9) + j];
        const float4* tp = (const float4*)(t3 + ((size_t)row << 7) + b0);
        float4 t0 = tp[0], t1 = tp[1];
        a0 = fmaf(t0.x, wv, a0);
        a1 = fmaf(t0.y, wv, a1);
        a2 = fmaf(t0.z, wv, a2);
        a3 = fmaf(t0.w, wv, a3);
        a4 = fmaf(t1.x, wv, a4);
        a5 = fmaf(t1.y, wv, a5);
        a6 = fmaf(t1.z, wv, a6);
        a7 = fmaf(t1.w, wv, a7);
    }
    float* pp = part + (((size_t)(rs << 7) + b0) << 9) + j;
    pp[0*512]=a0; pp[1*512]=a1; pp[2*512]=a2; pp[3*512]=a3;
    pp[4*512]=a4; pp[5*512]=a5; pp[6*512]=a6; pp[7*512]=a7;
}

__global__ __launch_bounds__(256) void k_fc1_red(const float* __restrict__ part, const float* __restrict__ bias,
                          float* __restrict__ h) {
    int i = blockIdx.x * 256 + threadIdx.x;   // i = b*512 + j
    float a = bias[i & 511];
#pragma unroll 8
    for (int rs = 0; rs < 64; ++rs) a += part[((size_t)rs << 16) + i];
    h[i] = a;
}

// ---------------- batchnorm stats over batch (biased var), store mean | inv_std
__global__ void k_bnstats(const float* __restrict__ h, float* __restrict__ mv) {
    __shared__ float s1[128], s2[128];
    int j = blockIdx.x, t = threadIdx.x;
    float v = h[(size_t)t * 512 + j];
    s1[t] = v; s2[t] = v * v;
    __syncthreads();
    for (int o = 64; o > 0; o >>= 1) {
        if (t < o) { s1[t] += s1[t + o]; s2[t] += s2[t + o]; }
        __syncthreads();
    }
    if (t == 0) {
        float m = s1[0] * (1.f / 128.f);
        float var = s2[0] * (1.f / 128.f) - m * m;
        mv[j] = m;
        mv[512 + j] = rsqrtf(var + 1e-5f);
    }
}

// ---------------- BN apply + relu + FC2 + log_softmax, one block per batch row
__global__ void k_head(const float* __restrict__ h, const float* __restrict__ mv,
                       const float* __restrict__ gamma, const float* __restrict__ beta,
                       const float* __restrict__ w2, const float* __restrict__ b2,
                       float* __restrict__ out) {
    __shared__ float hr[512];
    __shared__ float lg[16];
    int b = blockIdx.x, t = threadIdx.x;   // 64 threads
    for (int j = t; j < 512; j += 64) {
        float x = (h[(size_t)b * 512 + j] - mv[j]) * mv[512 + j] * gamma[j] + beta[j];
        hr[j] = fmaxf(x, 0.f);
    }
    __syncthreads();
    if (t < 10) {
        float a = b2[t];
        for (int j = 0; j < 512; ++j) a += hr[j] * w2[j * 10 + t];
        lg[t] = a;
    }
    __syncthreads();
    if (t == 0) {
        float mx = -1e30f;
        for (int q = 0; q < 10; ++q) mx = fmaxf(mx, lg[q]);
        float sum = 0.f;
        for (int q = 0; q < 10; ++q) sum += expf(lg[q] - mx);
        float ls = logf(sum) + mx;
        for (int q = 0; q < 10; ++q) out[b * 10 + q] = lg[q] - ls;
    }
}

extern "C" void kernel_launch(void* const* d_in, const int* in_sizes, int n_in,
                              void* d_out, int out_size, void* d_ws, size_t ws_size,
                              hipStream_t stream) {
    (void)in_sizes; (void)n_in; (void)out_size; (void)ws_size;
    const float* x      = (const float*)d_in[0];
    const int*   l0cols = (const int*)d_in[2];
    const float* l0vals = (const float*)d_in[3];
    const int*   l2cols = (const int*)d_in[5];
    const float* l2vals = (const float*)d_in[6];
    const int*   l4cols = (const int*)d_in[8];
    const float* l4vals = (const float*)d_in[9];
    const float* w1   = (const float*)d_in[10];
    const float* b1   = (const float*)d_in[11];
    const float* w2   = (const float*)d_in[12];
    const float* b2   = (const float*)d_in[13];
    const float* w3   = (const float*)d_in[14];
    const float* b3   = (const float*)d_in[15];
    const float* fc1w = (const float*)d_in[16];
    const float* fc1b = (const float*)d_in[17];
    const float* gam  = (const float*)d_in[18];
    const float* bet  = (const float*)d_in[19];
    const float* fc2w = (const float*)d_in[20];
    const float* fc2b = (const float*)d_in[21];
    float* out = (float*)d_out;

    const size_t S1 = 4096 * 128;    // layer-1 basis slot (floats)
    const size_t S2 = 1024 * 4096;   // layer-2 state size (floats); mirror slot = S2/2 dwords
    const size_t S3 = 256 * 8192;    // layer-3 state size (floats); mirror slot = S3/2 dwords

    float* ws = (float*)d_ws;
    float* basis1 = ws;                                  // 25 slots of S1 (layer-1, fp32)
    float* st2A   = ws + 25 * S1;                        // layer-2 fp32 state, parity 0
    float* st2B   = st2A + S2;                           // parity 1
    unsigned* mir2 = (unsigned*)(st2B + S2);             // 5 slots of S2/2 dwords (also mir3 ring)
    float* tailp  = (float*)(mir2 + 5 * (S2 / 2));
    float* h      = tailp;                               // 65536
    float* mv     = h + 65536;                           // 1024
    unsigned short* wb2 = (unsigned short*)(mv + 1024);  // 51200 bf16
    unsigned short* wb3 = wb2 + 51200;                   // 102400 bf16
    float* acc2   = basis1;                              // alias: basis1 dead after proj1
    float* st3A   = st2A;                                // alias: 2*S3 == S2, fits in st2A slot
    float* st3B   = st2A + S3;
    float* acc3   = st2B;                                // alias: layer-2 parity-1 state dead
    unsigned* mir3 = mir2;                               // S3/2-slot ring within mir2 region
    float* part   = basis1;                              // alias: acc2 dead by then

    k_packw<<<400, 256, 0, stream>>>(w2, w3, wb2, wb3);

    // ---------------- Layer 1: V=4096, C=128, full fp32 basis ----------------
    k_transpose_x<<<2048, 256, 0, stream>>>(x, basis1);
    for (int k = 1; k < 25; ++k) {
        const float* cur  = basis1 + (size_t)(k - 1) * S1;
        const float* prev = (k >= 2) ? basis1 + (size_t)(k - 2) * S1 : cur;
        float* next = basis1 + (size_t)k * S1;
        k_spmm1<<<512, 256, 0, stream>>>(l0cols, l0vals, (const float4*)cur,
                                         (const float4*)prev, (float4*)next, k >= 2 ? 1 : 0);
    }
    // pool1 -> st2A (fp32 T0, parity 0) + mir2 slot0
    k_proj1_pool<<<dim3(512, 2), 256, 0, stream>>>(basis1, w1, b1, st2A, mir2);

    // ---------------- Layer 2: V=1024, bf16-mirror gather, fp32 parity ping-pong ----------------
    {
        float* s2[2] = {st2A, st2B};
        int cs = 0;
        for (int k = 0; k < 25; ++k) {
            if (k >= 1) {
                k_spmm4m<4><<<2048, 256, 0, stream>>>(l2cols, l2vals,
                    mir2 + (size_t)((k - 1) % 5) * (S2 / 2), s2[k & 1],
                    mir2 + (size_t)(k % 5) * (S2 / 2), k >= 2 ? 1 : 0);
            }
            if (k - cs + 1 == 5) {
                k_proj_l2m<<<2048, 256, 0, stream>>>(mir2, S2 / 2, (const uint4*)wb2, acc2, cs,
                                                     cs == 0 ? 1 : 0, b2);
                cs = k + 1;
            }
        }
    }
    k_relu_pool_m<<<4096, 256, 0, stream>>>(acc2, st3A /*fp32 T0*/, mir3 /*slot0*/);

    // ---------------- Layer 3: V=256, bf16-mirror gather, fp32 parity ping-pong ----------------
    {
        float* s3[2] = {st3A, st3B};
        int cs = 0;
        for (int k = 0; k < 25; ++k) {
            if (k >= 1) {
                k_spmm4m<5><<<1024, 256, 0, stream>>>(l4cols, l4vals,
                    mir3 + (size_t)((k - 1) % 5) * (S3 / 2), s3[k & 1],
                    mir3 + (size_t)(k % 5) * (S3 / 2), k >= 2 ? 1 : 0);
            }
            if (k - cs + 1 == 5) {
                k_proj_l3m<<<512, 256, 0, stream>>>(mir3, S3 / 2, (const uint4*)wb3, acc3, cs,
                                                    cs == 0 ? 1 : 0, b3, cs == 20 ? 1 : 0);
                cs = k + 1;
            }
        }
    }

    // ---------------- FC1 + BN + FC2 + log_softmax ----------------
    k_fc1_part<<<2048, 256, 0, stream>>>(acc3, fc1w, part);
    k_fc1_red<<<256, 256, 0, stream>>>(part, fc1b, h);
    k_bnstats<<<512, 128, 0, stream>>>(h, mv);
    k_head<<<128, 64, 0, stream>>>(h, mv, gam, bet, fc2w, fc2b, out);
}

// Round 15
// 806.974 us; speedup vs baseline: 1.4325x; 1.0016x over previous
//
#include <hip/hip_runtime.h>

#define B_ 128
#define K_ 25
#define DEG_ 16

#define R4(X) X(0) X(1) X(2) X(3)
#define R16(X) X(0) X(1) X(2) X(3) X(4) X(5) X(6) X(7) X(8) X(9) X(10) X(11) X(12) X(13) X(14) X(15)

typedef __attribute__((ext_vector_type(4))) float f32x4;
typedef __attribute__((ext_vector_type(8))) short bf16x8;

__device__ __forceinline__ float4 f4ma(float t, float4 w, float4 a) {
    a.x = fmaf(t, w.x, a.x); a.y = fmaf(t, w.y, a.y);
    a.z = fmaf(t, w.z, a.z); a.w = fmaf(t, w.w, a.w);
    return a;
}
__device__ __forceinline__ float4 f4max(float4 a, float4 b) {
    return make_float4(fmaxf(a.x, b.x), fmaxf(a.y, b.y), fmaxf(a.z, b.z), fmaxf(a.w, b.w));
}
__device__ __forceinline__ float4 f4add(float4 a, float4 b) {
    return make_float4(a.x + b.x, a.y + b.y, a.z + b.z, a.w + b.w);
}
__device__ __forceinline__ float4 f4sub2(float4 s, float4 p) {
    return make_float4(2.f * s.x - p.x, 2.f * s.y - p.y, 2.f * s.z - p.z, 2.f * s.w - p.w);
}
// bf16 pack (RTNE)
__device__ __forceinline__ unsigned f2bfu(float f) {
    unsigned u = __float_as_uint(f);
    return (u + 0x7FFFu + ((u >> 16) & 1u)) >> 16;
}
__device__ __forceinline__ unsigned packbf(float e, float o) { return f2bfu(e) | (f2bfu(o) << 16); }
// mirror dword -> even/odd floats
__device__ __forceinline__ float4 mevens(uint4 m) {
    return make_float4(__uint_as_float(m.x << 16), __uint_as_float(m.y << 16),
                       __uint_as_float(m.z << 16), __uint_as_float(m.w << 16));
}
__device__ __forceinline__ float4 modds(uint4 m) {
    return make_float4(__uint_as_float(m.x & 0xFFFF0000u), __uint_as_float(m.y & 0xFFFF0000u),
                       __uint_as_float(m.z & 0xFFFF0000u), __uint_as_float(m.w & 0xFFFF0000u));
}

__device__ __forceinline__ bf16x8 u2b(uint4 u) {
    union { uint4 u4; bf16x8 b8; } c; c.u4 = u; return c.b8;
}
__device__ __forceinline__ f32x4 mfma_bf(uint4 a, uint4 b, f32x4 c) {
    return __builtin_amdgcn_mfma_f32_16x16x32_bf16(u2b(a), u2b(b), c, 0, 0, 0);
}

// ---------------- transpose x: (B=128, N=4096) -> x0 (4096, 128) + T0 bf16 mirror
// mirror1 layout: [v][64] dwords, dword d = packbf(x[v][2d], x[v][2d+1])
__global__ __launch_bounds__(256) void k_transpose_xm(const float* __restrict__ x,
        float* __restrict__ x0, unsigned* __restrict__ mir) {
    int i = blockIdx.x * 256 + threadIdx.x;   // i = v*64 + bp, total 262144
    int v = i >> 6, bp = i & 63;
    float e = x[((size_t)(2 * bp) << 12) + v];
    float o = x[((size_t)(2 * bp + 1) << 12) + v];
    x0[(v << 7) + 2 * bp] = e;
    x0[(v << 7) + 2 * bp + 1] = o;
    mir[(v << 6) + bp] = packbf(e, o);
}

// ---------------- prepack W2/W3 -> bf16 [k][fo][fi]
__global__ __launch_bounds__(256) void k_packw(const float* __restrict__ w2, const float* __restrict__ w3,
        unsigned short* __restrict__ wb2, unsigned short* __restrict__ wb3) {
    int i = blockIdx.x * 256 + threadIdx.x;
    if (i < 51200) {        // 25*64*32
        int k = i >> 11, rem = i & 2047, fo = rem >> 5, fi = rem & 31;
        wb2[i] = (unsigned short)f2bfu(w2[(size_t)(fi * K_ + k) * 64 + fo]);
    }
    if (i < 102400) {       // 25*64*64
        int k = i >> 12, rem = i & 4095, fo = rem >> 6, fi = rem & 63;
        wb3[i] = (unsigned short)f2bfu(w3[(size_t)(fi * K_ + k) * 64 + fo]);
    }
}

// ---------------- layer-1 SpMM via bf16 mirror: thread owns (v, slab of 4 dwords = 8 b)
// gather uint4 from mirror of k-1; prev/next fp32 in basis1 slots (proj1 needs fp32 basis)
__global__ __launch_bounds__(256) void k_spmm1m(const int* __restrict__ cols, const float* __restrict__ vals,
        const unsigned* __restrict__ mirPrev, const float* __restrict__ prevF,
        float* __restrict__ nextF, unsigned* __restrict__ mirOut, int two) {
    int i = blockIdx.x * 256 + threadIdx.x;   // 65536: v = i>>4, sl = i&15
    int v = i >> 4, sl = i & 15;
    int base = v * DEG_;
    int moff = sl << 2;
    float4 eA = make_float4(0.f, 0.f, 0.f, 0.f), oA = eA, eB = eA, oB = eA;
#pragma unroll
    for (int d = 0; d < 8; ++d) {
        {
            float w = vals[base + d];
            uint4 m = *(const uint4*)(mirPrev + ((size_t)cols[base + d] << 6) + moff);
            eA = f4ma(w, mevens(m), eA); oA = f4ma(w, modds(m), oA);
        }
        {
            float w = vals[base + 8 + d];
            uint4 m = *(const uint4*)(mirPrev + ((size_t)cols[base + 8 + d] << 6) + moff);
            eB = f4ma(w, mevens(m), eB); oB = f4ma(w, modds(m), oB);
        }
    }
    float4 e = f4add(eA, eB), o = f4add(oA, oB);
    float4 f0 = make_float4(e.x, o.x, e.y, o.y);
    float4 f1 = make_float4(e.z, o.z, e.w, o.w);
    size_t sidx = ((size_t)v << 7) + (sl << 3);
    if (two) {
        float4 p0 = *(const float4*)(prevF + sidx), p1 = *(const float4*)(prevF + sidx + 4);
        f0 = f4sub2(f0, p0); f1 = f4sub2(f1, p1);
    }
    *(float4*)(nextF + sidx) = f0;
    *(float4*)(nextF + sidx + 4) = f1;
    *(uint4*)(mirOut + ((size_t)v << 6) + moff) =
        make_uint4(packbf(f0.x, f0.y), packbf(f0.z, f0.w), packbf(f1.x, f1.y), packbf(f1.z, f1.w));
}

// ---------------- SpMM (layers 2/3) gathering from bf16 mirror; fp32 prev/next in-place
template<int LOGF2>
__global__ __launch_bounds__(256) void k_spmm4m(const int* __restrict__ cols, const float* __restrict__ vals,
        const unsigned* __restrict__ mirPrev, float* __restrict__ st,
        unsigned* __restrict__ mirOut, int two) {
    constexpr int SL = LOGF2 + 2;                 // threads per (v, slab)
    constexpr int MSTR = 1 << (LOGF2 + 7);        // mirror v-stride (dwords)
    int xcd = blockIdx.x & 7, q = blockIdx.x >> 3;
    int v = __builtin_amdgcn_readfirstlane((q << (8 - SL)) + (threadIdx.x >> SL));
    int l = threadIdx.x & ((1 << SL) - 1);
    int cc = (xcd << SL) + l;
    int fi2 = cc >> 5, b0 = (cc & 31) << 2;
    int base = v * DEG_;
    int moff = (fi2 << 7) + b0;
    float4 eA = make_float4(0.f, 0.f, 0.f, 0.f), eB = eA, oA = eA, oB = eA;
#pragma unroll
    for (int d = 0; d < 8; ++d) {
        {
            float w = vals[base + d];
            uint4 m = *(const uint4*)(mirPrev + (size_t)cols[base + d] * MSTR + moff);
            eA = f4ma(w, mevens(m), eA); oA = f4ma(w, modds(m), oA);
        }
        {
            float w = vals[base + 8 + d];
            uint4 m = *(const uint4*)(mirPrev + (size_t)cols[base + 8 + d] * MSTR + moff);
            eB = f4ma(w, mevens(m), eB); oB = f4ma(w, modds(m), oB);
        }
    }
    float4 e = f4add(eA, eB), o = f4add(oA, oB);
    size_t sidx = ((size_t)v << (LOGF2 + 8)) + (fi2 << 8) + b0;
    if (two) {
        float4 pe = *(const float4*)(st + sidx), po = *(const float4*)(st + sidx + 128);
        e = f4sub2(e, pe); o = f4sub2(o, po);
    }
    *(float4*)(st + sidx) = e;
    *(float4*)(st + sidx + 128) = o;
    *(uint4*)(mirOut + (size_t)v * MSTR + moff) =
        make_uint4(packbf(e.x, o.x), packbf(e.y, o.y), packbf(e.z, o.z), packbf(e.w, o.w));
}

// ---------------- layer 1 projection (Fin=1, Fout=32) + bias + relu + pool4 (+ bf16 mirror)
__global__ __launch_bounds__(256) void k_proj1_pool(const float* __restrict__ basis,
        const float* __restrict__ W1, const float* __restrict__ b1, float* __restrict__ pool1,
        unsigned* __restrict__ mir) {
    int half = blockIdx.y;
    int i = blockIdx.x * 256 + threadIdx.x;   // i = g*128 + b
    int g = i >> 7, b = i & 127;
    const float* wbase = W1 + half * 16;
#define P1_DM(j) float4 M##j = make_float4(-1e30f, -1e30f, -1e30f, -1e30f);
    R4(P1_DM)
#undef P1_DM
    for (int r = 0; r < 4; ++r) {
        const float* bp = basis + (((size_t)(4 * g + r) << 7) + b);
#define P1_DC(j) float4 C##j = make_float4(0.f, 0.f, 0.f, 0.f);
        R4(P1_DC)
#undef P1_DC
#pragma unroll 5
        for (int k = 0; k < K_; ++k) {
            float tv = bp[(size_t)k * 524288];
            const float4* w = (const float4*)(wbase + k * 32);
#define P1_FM(j) C##j = f4ma(tv, w[j], C##j);
            R4(P1_FM)
#undef P1_FM
        }
#define P1_MX(j) M##j = f4max(M##j, C##j);
        R4(P1_MX)
#undef P1_MX
    }
    float* op = pool1 + ((size_t)g << 12) + ((size_t)half << 11) + b;
    unsigned* mp = mir + ((size_t)g << 11) + ((size_t)half << 10) + b;
    const float* bb = b1 + half * 16;
#define P1_ST(j) { \
    float e0 = fmaxf(M##j.x + bb[4*j+0], 0.f); \
    float o0 = fmaxf(M##j.y + bb[4*j+1], 0.f); \
    float e1 = fmaxf(M##j.z + bb[4*j+2], 0.f); \
    float o1 = fmaxf(M##j.w + bb[4*j+3], 0.f); \
    op[(4*j+0)*128] = e0; op[(4*j+1)*128] = o0; \
    op[(4*j+2)*128] = e1; op[(4*j+3)*128] = o1; \
    mp[(2*j+0)*128] = packbf(e0, o0); \
    mp[(2*j+1)*128] = packbf(e1, o1); }
    R4(P1_ST)
#undef P1_ST
}

// ---------------- layer-2 chunk projection via MFMA: one wave = 16 b x 64 fo, K=5kk*32fi
__global__ __launch_bounds__(256) void k_proj_l2m(const unsigned* __restrict__ mir, size_t slotH,
        const uint4* __restrict__ wb, float* __restrict__ acc, int k0, int init,
        const float* __restrict__ bias) {
    int wid = blockIdx.x * 4 + (threadIdx.x >> 6);   // 8192 waves
    int lane = threadIdx.x & 63;
    int lm = lane & 15, lg = lane >> 4;
    int v = wid >> 3, b0 = (wid & 7) << 4;
    float* ap = acc + ((size_t)v << 13) + b0 + (lg << 2);
    f32x4 C0, C1, C2, C3;
    if (init) {
        float q0 = bias[lm], q1 = bias[16 + lm], q2 = bias[32 + lm], q3 = bias[48 + lm];
        C0 = f32x4{q0, q0, q0, q0}; C1 = f32x4{q1, q1, q1, q1};
        C2 = f32x4{q2, q2, q2, q2}; C3 = f32x4{q3, q3, q3, q3};
    } else {
        C0 = *(const f32x4*)(ap + (size_t)lm * 128);
        C1 = *(const f32x4*)(ap + (size_t)(16 + lm) * 128);
        C2 = *(const f32x4*)(ap + (size_t)(32 + lm) * 128);
        C3 = *(const f32x4*)(ap + (size_t)(48 + lm) * 128);
    }
    const unsigned* mp0 = mir + ((size_t)v << 11) + (lg << 9) + b0 + lm;
#pragma unroll
    for (int kk = 0; kk < 5; ++kk) {
        const unsigned* mp = mp0 + (size_t)kk * slotH;
        uint4 a = make_uint4(mp[0], mp[128], mp[256], mp[384]);
        int kb = (k0 + kk) << 6;
        uint4 w0 = wb[(kb + lm) * 4 + lg];
        uint4 w1 = wb[(kb + 16 + lm) * 4 + lg];
        uint4 w2 = wb[(kb + 32 + lm) * 4 + lg];
        uint4 w3 = wb[(kb + 48 + lm) * 4 + lg];
        C0 = mfma_bf(a, w0, C0);
        C1 = mfma_bf(a, w1, C1);
        C2 = mfma_bf(a, w2, C2);
        C3 = mfma_bf(a, w3, C3);
    }
    *(f32x4*)(ap + (size_t)lm * 128) = C0;
    *(f32x4*)(ap + (size_t)(16 + lm) * 128) = C1;
    *(f32x4*)(ap + (size_t)(32 + lm) * 128) = C2;
    *(f32x4*)(ap + (size_t)(48 + lm) * 128) = C3;
}

// ---------------- layer-3 chunk projection via MFMA: Fin=64 -> 2 K-steps per kk
__global__ __launch_bounds__(256) void k_proj_l3m(const unsigned* __restrict__ mir, size_t slotH,
        const uint4* __restrict__ wb, float* __restrict__ acc, int k0, int init,
        const float* __restrict__ bias, int finalrelu) {
    int wid = blockIdx.x * 4 + (threadIdx.x >> 6);   // 2048 waves
    int lane = threadIdx.x & 63;
    int lm = lane & 15, lg = lane >> 4;
    int v = wid >> 3, b0 = (wid & 7) << 4;
    float* ap = acc + ((size_t)v << 13) + b0 + (lg << 2);
    f32x4 C0, C1, C2, C3;
    if (init) {
        float q0 = bias[lm], q1 = bias[16 + lm], q2 = bias[32 + lm], q3 = bias[48 + lm];
        C0 = f32x4{q0, q0, q0, q0}; C1 = f32x4{q1, q1, q1, q1};
        C2 = f32x4{q2, q2, q2, q2}; C3 = f32x4{q3, q3, q3, q3};
    } else {
        C0 = *(const f32x4*)(ap + (size_t)lm * 128);
        C1 = *(const f32x4*)(ap + (size_t)(16 + lm) * 128);
        C2 = *(const f32x4*)(ap + (size_t)(32 + lm) * 128);
        C3 = *(const f32x4*)(ap + (size_t)(48 + lm) * 128);
    }
    const unsigned* mp0 = mir + ((size_t)v << 12) + b0 + lm;
#pragma unroll
    for (int kk = 0; kk < 5; ++kk) {
        const unsigned* mp = mp0 + (size_t)kk * slotH;
        int kb = (k0 + kk) << 6;
#pragma unroll
        for (int ks = 0; ks < 2; ++ks) {
            const unsigned* mk = mp + (size_t)((ks << 4) + (lg << 2)) * 128;
            uint4 a = make_uint4(mk[0], mk[128], mk[256], mk[384]);
            int wof = (ks << 2) + lg;
            uint4 w0 = wb[(kb + lm) * 8 + wof];
            uint4 w1 = wb[(kb + 16 + lm) * 8 + wof];
            uint4 w2 = wb[(kb + 32 + lm) * 8 + wof];
            uint4 w3 = wb[(kb + 48 + lm) * 8 + wof];
            C0 = mfma_bf(a, w0, C0);
            C1 = mfma_bf(a, w1, C1);
            C2 = mfma_bf(a, w2, C2);
            C3 = mfma_bf(a, w3, C3);
        }
    }
    if (finalrelu) {
#pragma unroll
        for (int r = 0; r < 4; ++r) {
            C0[r] = fmaxf(C0[r], 0.f); C1[r] = fmaxf(C1[r], 0.f);
            C2[r] = fmaxf(C2[r], 0.f); C3[r] = fmaxf(C3[r], 0.f);
        }
    }
    *(f32x4*)(ap + (size_t)lm * 128) = C0;
    *(f32x4*)(ap + (size_t)(16 + lm) * 128) = C1;
    *(f32x4*)(ap + (size_t)(32 + lm) * 128) = C2;
    *(f32x4*)(ap + (size_t)(48 + lm) * 128) = C3;
}

// ---------------- relu + pool4 + bf16 mirror (layer2 acc -> layer3 T0 state + mirror slot0)
__global__ __launch_bounds__(256) void k_relu_pool_m(const float* __restrict__ acc,
        float* __restrict__ pool, unsigned* __restrict__ mir) {
    int i = blockIdx.x * 256 + threadIdx.x;   // g*4096 + fi2*128 + b, total 1,048,576
    int g = i >> 12, fi2 = (i >> 7) & 31, b = i & 127;
    const float* ap = acc + (((size_t)g << 2) << 13) + (fi2 << 8) + b;
    float me = 0.f, mo = 0.f;
#pragma unroll
    for (int r = 0; r < 4; ++r) {
        me = fmaxf(me, ap[0]); mo = fmaxf(mo, ap[128]);
        ap += 8192;
    }
    size_t po = ((size_t)g << 13) + (fi2 << 8) + b;
    pool[po] = me; pool[po + 128] = mo;
    mir[i] = packbf(me, mo);
}

// ---------------- FC1 partials: rowsplit 64, 16 b's per thread, 1024 blocks
// blk = bg4*128 + rs*2 + jh  (same-w blocks stride 128 -> same XCD)
__global__ __launch_bounds__(256) void k_fc1_part(const float* __restrict__ t3, const float* __restrict__ w,
                           float* __restrict__ part) {
    int blk = blockIdx.x;
    int bg4 = blk >> 7;                        // 0..7
    int rs = (blk >> 1) & 63;
    int j = ((blk & 1) << 8) + threadIdx.x;
    int b0 = bg4 << 4;
#define FC_DA(q) float a##q = 0.f;
    R16(FC_DA)
#undef FC_DA
    int r0 = rs << 8;
#pragma unroll 4
    for (int row = r0; row < r0 + 256; ++row) {
        float wv = w[((size_t)row << 9) + j];
        const float4* tp = (const float4*)(t3 + ((size_t)row << 7) + b0);
        float4 t0 = tp[0], t1 = tp[1], t2 = tp[2], t3v = tp[3];
        a0 = fmaf(t0.x, wv, a0);   a1 = fmaf(t0.y, wv, a1);
        a2 = fmaf(t0.z, wv, a2);   a3 = fmaf(t0.w, wv, a3);
        a4 = fmaf(t1.x, wv, a4);   a5 = fmaf(t1.y, wv, a5);
        a6 = fmaf(t1.z, wv, a6);   a7 = fmaf(t1.w, wv, a7);
        a8 = fmaf(t2.x, wv, a8);   a9 = fmaf(t2.y, wv, a9);
        a10 = fmaf(t2.z, wv, a10); a11 = fmaf(t2.w, wv, a11);
        a12 = fmaf(t3v.x, wv, a12); a13 = fmaf(t3v.y, wv, a13);
        a14 = fmaf(t3v.z, wv, a14); a15 = fmaf(t3v.w, wv, a15);
    }
    float* pp = part + (((size_t)(rs << 7) + b0) << 9) + j;
#define FC_ST(q) pp[q * 512] = a##q;
    R16(FC_ST)
#undef FC_ST
}

__global__ __launch_bounds__(256) void k_fc1_red(const float* __restrict__ part, const float* __restrict__ bias,
                          float* __restrict__ h) {
    int i = blockIdx.x * 256 + threadIdx.x;   // i = b*512 + j
    float a = bias[i & 511];
#pragma unroll 8
    for (int rs = 0; rs < 64; ++rs) a += part[((size_t)rs << 16) + i];
    h[i] = a;
}

// ---------------- batchnorm stats over batch (biased var), store mean | inv_std
__global__ void k_bnstats(const float* __restrict__ h, float* __restrict__ mv) {
    __shared__ float s1[128], s2[128];
    int j = blockIdx.x, t = threadIdx.x;
    float v = h[(size_t)t * 512 + j];
    s1[t] = v; s2[t] = v * v;
    __syncthreads();
    for (int o = 64; o > 0; o >>= 1) {
        if (t < o) { s1[t] += s1[t + o]; s2[t] += s2[t + o]; }
        __syncthreads();
    }
    if (t == 0) {
        float m = s1[0] * (1.f / 128.f);
        float var = s2[0] * (1.f / 128.f) - m * m;
        mv[j] = m;
        mv[512 + j] = rsqrtf(var + 1e-5f);
    }
}

// ---------------- BN apply + relu + FC2 + log_softmax, one block per batch row
__global__ void k_head(const float* __restrict__ h, const float* __restrict__ mv,
                       const float* __restrict__ gamma, const float* __restrict__ beta,
                       const float* __restrict__ w2, const float* __restrict__ b2,
                       float* __restrict__ out) {
    __shared__ float hr[512];
    __shared__ float lg[16];
    int b = blockIdx.x, t = threadIdx.x;   // 64 threads
    for (int j = t; j < 512; j += 64) {
        float x = (h[(size_t)b * 512 + j] - mv[j]) * mv[512 + j] * gamma[j] + beta[j];
        hr[j] = fmaxf(x, 0.f);
    }
    __syncthreads();
    if (t < 10) {
        float a = b2[t];
        for (int j = 0; j < 512; ++j) a += hr[j] * w2[j * 10 + t];
        lg[t] = a;
    }
    __syncthreads();
    if (t == 0) {
        float mx = -1e30f;
        for (int q = 0; q < 10; ++q) mx = fmaxf(mx, lg[q]);
        float sum = 0.f;
        for (int q = 0; q < 10; ++q) sum += expf(lg[q] - mx);
        float ls = logf(sum) + mx;
        for (int q = 0; q < 10; ++q) out[b * 10 + q] = lg[q] - ls;
    }
}

extern "C" void kernel_launch(void* const* d_in, const int* in_sizes, int n_in,
                              void* d_out, int out_size, void* d_ws, size_t ws_size,
                              hipStream_t stream) {
    (void)in_sizes; (void)n_in; (void)out_size; (void)ws_size;
    const float* x      = (const float*)d_in[0];
    const int*   l0cols = (const int*)d_in[2];
    const float* l0vals = (const float*)d_in[3];
    const int*   l2cols = (const int*)d_in[5];
    const float* l2vals = (const float*)d_in[6];
    const int*   l4cols = (const int*)d_in[8];
    const float* l4vals = (const float*)d_in[9];
    const float* w1   = (const float*)d_in[10];
    const float* b1   = (const float*)d_in[11];
    const float* w2   = (const float*)d_in[12];
    const float* b2   = (const float*)d_in[13];
    const float* w3   = (const float*)d_in[14];
    const float* b3   = (const float*)d_in[15];
    const float* fc1w = (const float*)d_in[16];
    const float* fc1b = (const float*)d_in[17];
    const float* gam  = (const float*)d_in[18];
    const float* bet  = (const float*)d_in[19];
    const float* fc2w = (const float*)d_in[20];
    const float* fc2b = (const float*)d_in[21];
    float* out = (float*)d_out;

    const size_t S1 = 4096 * 128;    // layer-1 basis slot (floats); mirror slot = S1/2 dwords
    const size_t S2 = 1024 * 4096;   // layer-2 state size (floats); mirror slot = S2/2 dwords
    const size_t S3 = 256 * 8192;    // layer-3 state size (floats); mirror slot = S3/2 dwords

    float* ws = (float*)d_ws;
    float* basis1 = ws;                                  // 25 slots of S1 (layer-1, fp32)
    float* st2A   = ws + 25 * S1;                        // layer-2 fp32 state, parity 0
    float* st2B   = st2A + S2;                           // parity 1
    unsigned* mir2 = (unsigned*)(st2B + S2);             // 5 slots of S2/2 dwords (also mir3 ring)
    float* tailp  = (float*)(mir2 + 5 * (S2 / 2));
    float* h      = tailp;                               // 65536
    float* mv     = h + 65536;                           // 1024
    unsigned short* wb2 = (unsigned short*)(mv + 1024);  // 51200 bf16
    unsigned short* wb3 = wb2 + 51200;                   // 102400 bf16
    unsigned* mir1 = (unsigned*)(wb3 + 102400);          // 2 slots of S1/2 dwords (layer-1 mirror)
    float* acc2   = basis1;                              // alias: basis1 dead after proj1
    float* st3A   = st2A;                                // alias: 2*S3 == S2, fits in st2A slot
    float* st3B   = st2A + S3;
    float* acc3   = st2B;                                // alias: layer-2 parity-1 state dead
    unsigned* mir3 = mir2;                               // S3/2-slot ring within mir2 region
    float* part   = basis1;                              // alias: acc2 dead by then

    k_packw<<<400, 256, 0, stream>>>(w2, w3, wb2, wb3);

    // ---------------- Layer 1: V=4096, C=128, bf16-mirror gather, fp32 basis kept ----------------
    k_transpose_xm<<<1024, 256, 0, stream>>>(x, basis1, mir1 /*T0 mirror, slot 0*/);
    for (int k = 1; k < 25; ++k) {
        const float* prevF = (k >= 2) ? basis1 + (size_t)(k - 2) * S1 : basis1;
        float* nextF = basis1 + (size_t)k * S1;
        k_spmm1m<<<256, 256, 0, stream>>>(l0cols, l0vals,
            mir1 + (size_t)((k - 1) & 1) * (S1 / 2), prevF, nextF,
            mir1 + (size_t)(k & 1) * (S1 / 2), k >= 2 ? 1 : 0);
    }
    // pool1 -> st2A (fp32 T0, parity 0) + mir2 slot0
    k_proj1_pool<<<dim3(512, 2), 256, 0, stream>>>(basis1, w1, b1, st2A, mir2);

    // ---------------- Layer 2: V=1024, bf16-mirror gather, fp32 parity ping-pong ----------------
    {
        float* s2[2] = {st2A, st2B};
        int cs = 0;
        for (int k = 0; k < 25; ++k) {
            if (k >= 1) {
                k_spmm4m<4><<<2048, 256, 0, stream>>>(l2cols, l2vals,
                    mir2 + (size_t)((k - 1) % 5) * (S2 / 2), s2[k & 1],
                    mir2 + (size_t)(k % 5) * (S2 / 2), k >= 2 ? 1 : 0);
            }
            if (k - cs + 1 == 5) {
                k_proj_l2m<<<2048, 256, 0, stream>>>(mir2, S2 / 2, (const uint4*)wb2, acc2, cs,
                                                     cs == 0 ? 1 : 0, b2);
                cs = k + 1;
            }
        }
    }
    k_relu_pool_m<<<4096, 256, 0, stream>>>(acc2, st3A /*fp32 T0*/, mir3 /*slot0*/);

    // ---------------- Layer 3: V=256, bf16-mirror gather, fp32 parity ping-pong ----------------
    {
        float* s3[2] = {st3A, st3B};
        int cs = 0;
        for (int k = 0; k < 25; ++k) {
            if (k >= 1) {
                k_spmm4m<5><<<1024, 256, 0, stream>>>(l4cols, l4vals,
                    mir3 + (size_t)((k - 1) % 5) * (S3 / 2), s3[k & 1],
                    mir3 + (size_t)(k % 5) * (S3 / 2), k >= 2 ? 1 : 0);
            }
            if (k - cs + 1 == 5) {
                k_proj_l3m<<<512, 256, 0, stream>>>(mir3, S3 / 2, (const uint4*)wb3, acc3, cs,
                                                    cs == 0 ? 1 : 0, b3, cs == 20 ? 1 : 0);
                cs = k + 1;
            }
        }
    }

    // ---------------- FC1 + BN + FC2 + log_softmax ----------------
    k_fc1_part<<<1024, 256, 0, stream>>>(acc3, fc1w, part);
    k_fc1_red<<<256, 256, 0, stream>>>(part, fc1b, h);
    k_bnstats<<<512, 128, 0, stream>>>(h, mv);
    k_head<<<128, 64, 0, stream>>>(h, mv, gam, bet, fc2w, fc2b, out);
}